// Round 8
// baseline (873.041 us; speedup 1.0000x reference)
//
#include <hip/hip_runtime.h>
#include <hip/hip_bf16.h>
#include <stdint.h>

typedef long long ll;
typedef unsigned short ushort_t;
typedef __attribute__((ext_vector_type(8))) short bf16x8;
typedef __attribute__((ext_vector_type(4))) float f32x4;

static inline int cdiv_ll(ll a, ll b) { return (int)((a + b - 1) / b); }

#define BIN_SHIFT 8
#define BIN_SIZE 256
#define KMAX 3072         // max buckets over M2 (M2 <= 786K)
#define BT 1024           // binning block threads (16 waves)
#define FILL_CAP 7936     // staged edges per bucket (63.5 KB LDS)

// ---------------- dtype detection (bf16 vs fp32 inputs) ----------------
__global__ void k_detect(const unsigned int* __restrict__ dw, const ll n_dw, int* __restrict__ flag) {
    __shared__ int sc[256];
    int tid = threadIdx.x;
    int cnt = 0;
    for (int s = 0; s < 32; s++) {
        ll idx = (ll)(s * 256 + tid);
        ll i = (idx * n_dw) / 8192;
        unsigned v = dw[i];
        unsigned lo = v & 0xFFFFu;
        unsigned ex = (lo >> 7) & 0xFFu;
        bool pl = (lo == 0u) || (lo == 0x8000u) || (ex >= 0x60u && ex <= 0x8Fu);
        cnt += pl ? 1 : 0;
    }
    sc[tid] = cnt;
    __syncthreads();
    for (int o = 128; o > 0; o >>= 1) { if (tid < o) sc[tid] += sc[tid + o]; __syncthreads(); }
    if (tid == 0) *flag = (sc[0] * 2 > 8192) ? 1 : 0;
}

__device__ __forceinline__ float load_in(const void* p, ll i, int isbf16) {
    if (isbf16) return __bfloat162float(((const __hip_bfloat16*)p)[i]);
    return ((const float*)p)[i];
}

__device__ __forceinline__ float bf2f(ushort_t u) {
    return __uint_as_float(((unsigned)u) << 16);
}
__device__ __forceinline__ ushort_t f2bf(float f) {
    unsigned u = __float_as_uint(f);
    unsigned r = (u + 0x7FFFu + ((u >> 16) & 1u)) >> 16;
    return (ushort_t)r;
}

// ---------------- fused weight conversion ----------------
__global__ void k_cvt_weights(const void* __restrict__ W1u, const void* __restrict__ b1u,
                              const void* __restrict__ w2u, const void* __restrict__ W1i,
                              const void* __restrict__ b1i, const void* __restrict__ w2i,
                              ushort_t* __restrict__ Wbu, float* __restrict__ fb1u,
                              float* __restrict__ fw2u, ushort_t* __restrict__ Wbi,
                              float* __restrict__ fb1i, float* __restrict__ fw2i,
                              const int* __restrict__ flag) {
    int i = blockIdx.x * blockDim.x + threadIdx.x;
    int bf = *flag;
    const int WSZ = 64 * 128;
    if (i < WSZ) {
        int d = i >> 7, h = i & 127;
        Wbu[h * 64 + d] = f2bf(load_in(W1u, i, bf));
    } else if (i < WSZ + 128) {
        fb1u[i - WSZ] = load_in(b1u, i - WSZ, bf);
    } else if (i < WSZ + 256) {
        fw2u[i - WSZ - 128] = load_in(w2u, i - WSZ - 128, bf);
    } else if (i < 2 * WSZ + 256) {
        int j = i - WSZ - 256;
        int d = j >> 7, h = j & 127;
        Wbi[h * 64 + d] = f2bf(load_in(W1i, j, bf));
    } else if (i < 2 * WSZ + 384) {
        fb1i[i - 2 * WSZ - 256] = load_in(b1i, i - 2 * WSZ - 256, bf);
    } else if (i < 2 * WSZ + 512) {
        fw2i[i - 2 * WSZ - 384] = load_in(w2i, i - 2 * WSZ - 384, bf);
    }
}

// ---------------- record decode (in-CSR + out-deg records, M2 keyspace) ----
__device__ __forceinline__ void decode_rec(ll t,
    const int* __restrict__ uiR, const int* __restrict__ uiC,
    const int* __restrict__ u1s, const int* __restrict__ u1d,
    const int* __restrict__ u2s, const int* __restrict__ u2d,
    const int* __restrict__ i1s, const int* __restrict__ i1d,
    const int* __restrict__ i2s, const int* __restrict__ i2d,
    const ll E2, const ll EU1, const ll EU2, const ll EI1, const ll EI2,
    const int N, const int U, const int I, const int M,
    int& key, int& col) {
    if (t < E2) { key = uiR[t]; col = uiC[t]; return; }
    t -= E2;
    if (t < EU1) { key = N + u1d[t]; col = u1s[t]; return; }
    t -= EU1;
    if (t < EU1) { key = M + u1s[t]; col = 0; return; }
    t -= EU1;
    if (t < EU2) { key = N + U + u2d[t]; col = u2s[t]; return; }
    t -= EU2;
    if (t < EU2) { key = M + U + u2s[t]; col = 0; return; }
    t -= EU2;
    if (t < EI1) { key = N + 2 * U + i1d[t]; col = i1s[t]; return; }
    t -= EI1;
    if (t < EI1) { key = M + 2 * U + i1s[t]; col = 0; return; }
    t -= EI1;
    if (t < EI2) { key = N + 2 * U + I + i2d[t]; col = i2s[t]; return; }
    t -= EI2;
    key = M + 2 * U + I + i2s[t]; col = 0;
}

// key-only decode (histogram pass never needs col)
__device__ __forceinline__ int decode_key(ll t,
    const int* __restrict__ uiR,
    const int* __restrict__ u1s, const int* __restrict__ u1d,
    const int* __restrict__ u2s, const int* __restrict__ u2d,
    const int* __restrict__ i1s, const int* __restrict__ i1d,
    const int* __restrict__ i2s, const int* __restrict__ i2d,
    const ll E2, const ll EU1, const ll EU2, const ll EI1, const ll EI2,
    const int N, const int U, const int I, const int M) {
    if (t < E2) return uiR[t];
    t -= E2;
    if (t < EU1) return N + u1d[t];
    t -= EU1;
    if (t < EU1) return M + u1s[t];
    t -= EU1;
    if (t < EU2) return N + U + u2d[t];
    t -= EU2;
    if (t < EU2) return M + U + u2s[t];
    t -= EU2;
    if (t < EI1) return N + 2 * U + i1d[t];
    t -= EI1;
    if (t < EI1) return M + 2 * U + i1s[t];
    t -= EI1;
    if (t < EI2) return N + 2 * U + I + i2d[t];
    t -= EI2;
    return M + 2 * U + I + i2s[t];
}

#define DECODE_ARGS uiR, uiC, u1s, u1d, u2s, u2d, i1s, i1d, i2s, i2d, \
                    E2, EU1, EU2, EI1, EI2, N, U, I, M

// ---------------- pass A1: per-WG LDS histogram ----------------
// CHUNKD is dynamic (~RT/252 records/WG): scatter write traffic = runs x 64B,
// runs = (RT/CHUNKD) x K, so bigger chunks directly cut partial-line
// writebacks. Persists per-WG histogram (whist) for the scatter pass.
__global__ __launch_bounds__(BT) void kA_hist(
    const int* __restrict__ uiR,
    const int* __restrict__ u1s, const int* __restrict__ u1d,
    const int* __restrict__ u2s, const int* __restrict__ u2d,
    const int* __restrict__ i1s, const int* __restrict__ i1d,
    const int* __restrict__ i2s, const int* __restrict__ i2d,
    const ll E2, const ll EU1, const ll EU2, const ll EI1, const ll EI2,
    const int N, const int U, const int I, const int M,
    const ll RT, const ll CHUNKD, const int K,
    int* __restrict__ btot /* K*32 line-padded */,
    int* __restrict__ whist /* nWG x K */) {
    __shared__ int hist[KMAX];
    for (int i = threadIdx.x; i < K; i += BT) hist[i] = 0;
    __syncthreads();
    ll base = (ll)blockIdx.x * CHUNKD;
    ll lim = base + CHUNKD;
    if (lim > RT) lim = RT;
    for (ll t = base + threadIdx.x; t < lim; t += BT) {
        int key = decode_key(t, uiR, u1s, u1d, u2s, u2d, i1s, i1d, i2s, i2d,
                             E2, EU1, EU2, EI1, EI2, N, U, I, M);
        atomicAdd(&hist[key >> BIN_SHIFT], 1);
    }
    __syncthreads();
    ll wb = (ll)blockIdx.x * K;
    for (int k = threadIdx.x; k < K; k += BT) {
        int h = hist[k];
        whist[wb + k] = h;
        if (h) atomicAdd(&btot[k * 32], h);
    }
}

// ---------------- bucket scan: totals -> bases, init cursors ----------------
__global__ __launch_bounds__(1024) void k_bscan(const int* __restrict__ btot,
                                                int* __restrict__ bbase,
                                                int* __restrict__ bcursor, const int K) {
    __shared__ int sh[1024];
    __shared__ int carry;
    int t = threadIdx.x;
    if (t == 0) carry = 0;
    __syncthreads();
    for (int base = 0; base < K; base += 1024) {
        int idx = base + t;
        int v = (idx < K) ? btot[idx * 32] : 0;
        sh[t] = v;
        __syncthreads();
        for (int off = 1; off < 1024; off <<= 1) {
            int x = (t >= off) ? sh[t - off] : 0;
            __syncthreads();
            sh[t] += x;
            __syncthreads();
        }
        if (idx < K) {
            int ex = carry + sh[t] - v;
            bbase[idx] = ex;
            bcursor[idx * 32] = ex;
        }
        __syncthreads();
        if (t == 0) carry += sh[1023];
        __syncthreads();
    }
}

// ---------------- pass A2: scatter (single decode pass) -------
// Per-WG bucket counts from whist; records packed to 4B:
// (key & 255) << 24 | col  -- bucket id implicit from position.
__global__ __launch_bounds__(BT) void kA_scatter(
    const int* __restrict__ uiR, const int* __restrict__ uiC,
    const int* __restrict__ u1s, const int* __restrict__ u1d,
    const int* __restrict__ u2s, const int* __restrict__ u2d,
    const int* __restrict__ i1s, const int* __restrict__ i1d,
    const int* __restrict__ i2s, const int* __restrict__ i2d,
    const ll E2, const ll EU1, const ll EU2, const ll EI1, const ll EI2,
    const int N, const int U, const int I, const int M,
    const ll RT, const ll CHUNKD, const int K, int* __restrict__ bcursor,
    const int* __restrict__ whist,
    unsigned* __restrict__ binned) {
    __shared__ int lcur[KMAX];
    ll wb = (ll)blockIdx.x * K;
    for (int k = threadIdx.x; k < K; k += BT) {
        int h = whist[wb + k];
        lcur[k] = h ? atomicAdd(&bcursor[k * 32], h) : 0;
    }
    __syncthreads();
    ll base = (ll)blockIdx.x * CHUNKD;
    ll lim = base + CHUNKD;
    if (lim > RT) lim = RT;
    for (ll t = base + threadIdx.x; t < lim; t += BT) {
        int key, col;
        decode_rec(t, DECODE_ARGS, key, col);
        int pos = atomicAdd(&lcur[key >> BIN_SHIFT], 1);
        binned[pos] = ((unsigned)(key & 255) << 24) | (unsigned)col;
    }
}

// ---------------- pass B1: per-bucket LDS count -> counts array ----------
__global__ __launch_bounds__(256) void kB1_count(const unsigned* __restrict__ binned,
                                                 const int* __restrict__ bbase,
                                                 const int* __restrict__ btot,
                                                 int* __restrict__ counts, const int M2) {
    __shared__ int cnt[BIN_SIZE];
    int b = blockIdx.x;
    int lo = b << BIN_SHIFT;
    int hi = min(lo + BIN_SIZE, M2);
    for (int i = threadIdx.x; i < BIN_SIZE; i += 256) cnt[i] = 0;
    __syncthreads();
    int s = bbase[b], n = btot[b * 32];
    for (int j = s + threadIdx.x; j < s + n; j += 256) {
        atomicAdd(&cnt[binned[j] >> 24], 1);
    }
    __syncthreads();
    for (int i = threadIdx.x; i < hi - lo; i += 256) counts[lo + i] = cnt[i];
}

// ---------------- fused norms ----------------
__global__ void k_norm_all(const int* __restrict__ counts, float* __restrict__ nrm,
                           const int N, const int total) {
    int i = blockIdx.x * blockDim.x + threadIdx.x;
    if (i < total) {
        int c = counts[i];
        if (i < N) nrm[i] = (c > 0) ? (1.0f / sqrtf((float)c)) : 0.0f;
        else nrm[i] = 1.0f / sqrtf(fmaxf((float)c, 1.0f));
    }
}

// ---------------- hierarchical exclusive scan ----------
#define SCAN_T 256
#define SCAN_ELEMS 8
#define SCAN_CHUNK (SCAN_T * SCAN_ELEMS)   // 2048

__global__ __launch_bounds__(256) void k_scanA(const int* __restrict__ in, const int n,
                                               int* __restrict__ out, int* __restrict__ bsum) {
    __shared__ int sh[SCAN_T];
    int t = threadIdx.x;
    ll base = (ll)blockIdx.x * SCAN_CHUNK + (ll)t * SCAN_ELEMS;
    int v[SCAN_ELEMS];
    int tot = 0;
#pragma unroll
    for (int k = 0; k < SCAN_ELEMS; k++) {
        ll i = base + k;
        v[k] = (i < n) ? in[i] : 0;
        tot += v[k];
    }
    sh[t] = tot;
    __syncthreads();
    for (int off = 1; off < SCAN_T; off <<= 1) {
        int x = (t >= off) ? sh[t - off] : 0;
        __syncthreads();
        sh[t] += x;
        __syncthreads();
    }
    int run = sh[t] - tot;
#pragma unroll
    for (int k = 0; k < SCAN_ELEMS; k++) {
        ll i = base + k;
        if (i < n) out[i] = run;
        run += v[k];
    }
    if (t == SCAN_T - 1) bsum[blockIdx.x] = sh[SCAN_T - 1];
}

__global__ __launch_bounds__(256) void k_scanB(int* __restrict__ bsum, const int nb) {
    __shared__ int sh[256];
    int t = threadIdx.x;
    int running = 0;
    for (int base = 0; base < nb; base += 256) {
        int idx = base + t;
        int v = (idx < nb) ? bsum[idx] : 0;
        sh[t] = v;
        __syncthreads();
        for (int off = 1; off < 256; off <<= 1) {
            int x = (t >= off) ? sh[t - off] : 0;
            __syncthreads();
            sh[t] += x;
            __syncthreads();
        }
        if (idx < nb) bsum[idx] = running + sh[t] - v;
        int tot = sh[255];
        __syncthreads();
        running += tot;
    }
}

__global__ void k_scanC(int* __restrict__ S, const int n, const int* __restrict__ bsum, const int ET) {
    ll i = (ll)blockIdx.x * blockDim.x + threadIdx.x;
    if (i < n) S[i] += bsum[i / SCAN_CHUNK];
    if (i == 0) S[n] = ET;
}

// ---------------- pass B2: per-bucket CSR fill, LDS-staged ----------
__global__ __launch_bounds__(256) void kB2_fill(const unsigned* __restrict__ binned,
                                                const int* __restrict__ bbase,
                                                const int* __restrict__ btot,
                                                const int* __restrict__ S,
                                                const float* __restrict__ nrm,
                                                const int N, const int U, const int I,
                                                const int M,
                                                int2* __restrict__ ev_all) {
    __shared__ int scur[BIN_SIZE];
    __shared__ int2 buf[FILL_CAP];
    int b = blockIdx.x;
    int lo = b << BIN_SHIFT;
    int hi = min(lo + BIN_SIZE, M);
    int obase = S[lo];
    int nfill = S[hi] - obase;
    int s = bbase[b], n = btot[b * 32];
    const int segU = N + U, seg2U = N + 2 * U, segI = N + 2 * U + I;
    if (n <= FILL_CAP) {
        for (int i = threadIdx.x; i < hi - lo; i += 256) scur[i] = S[lo + i] - obase;
        __syncthreads();
        for (int j = s + threadIdx.x; j < s + n; j += 256) {
            unsigned rec = binned[j];
            int key = lo + (int)(rec >> 24);
            if (key < M) {
                int pos = atomicAdd(&scur[key - lo], 1);
                int col = (int)(rec & 0xFFFFFFu);
                int nidx;
                if (key < N)          nidx = col;                   // ui: dinv[col]
                else if (key < segU)  nidx = M + col;               // u1 src out-deg norm
                else if (key < seg2U) nidx = M + U + col;           // u2
                else if (key < segI)  nidx = M + 2 * U + col;       // i1
                else                  nidx = M + 2 * U + I + col;   // i2
                buf[pos] = make_int2(col * 64, __float_as_int(nrm[nidx]));
            }
        }
        __syncthreads();
        for (int i = threadIdx.x; i < nfill; i += 256)
            ev_all[obase + i] = buf[i];
    } else {
        // fallback: direct scatter (correct for any bucket size)
        for (int i = threadIdx.x; i < hi - lo; i += 256) scur[i] = S[lo + i];
        __syncthreads();
        for (int j = s + threadIdx.x; j < s + n; j += 256) {
            unsigned rec = binned[j];
            int key = lo + (int)(rec >> 24);
            if (key < M) {
                int pos = atomicAdd(&scur[key - lo], 1);
                int col = (int)(rec & 0xFFFFFFu);
                int nidx;
                if (key < N)          nidx = col;
                else if (key < segU)  nidx = M + col;
                else if (key < seg2U) nidx = M + U + col;
                else if (key < segI)  nidx = M + 2 * U + col;
                else                  nidx = M + 2 * U + I + col;
                ev_all[pos] = make_int2(col * 64, __float_as_int(nrm[nidx]));
            }
        }
    }
}

// ---------------- init features (bf16 storage) ----------------
__global__ void k_init(const void* __restrict__ uf, const void* __restrict__ itf,
                       ushort_t* __restrict__ ui, ushort_t* __restrict__ hu,
                       ushort_t* __restrict__ hi,
                       const ll nu64, const ll ntot64, const int* __restrict__ flag) {
    ll t = (ll)blockIdx.x * blockDim.x + threadIdx.x;
    int bf = *flag;
    if (t < nu64) {
        ushort_t v = bf ? ((const ushort_t*)uf)[t] : f2bf(((const float*)uf)[t]);
        ui[t] = v; hu[t] = v;
    } else if (t < ntot64) {
        ll j = t - nu64;
        ushort_t v = bf ? ((const ushort_t*)itf)[j] : f2bf(((const float*)itf)[j]);
        ui[t] = v; hi[j] = v;
    }
}

// ---------------- gather SpMM v2 ----------------
__global__ __launch_bounds__(256) void k_gather(const int* __restrict__ row_ptr,
                                                const int2* __restrict__ ev,
                                                const ushort_t* __restrict__ x,
                                                const float* __restrict__ rnorm,
                                                ushort_t* __restrict__ out, const int nrows) {
    ll gt = (ll)blockIdx.x * blockDim.x + threadIdx.x;
    int w = __builtin_amdgcn_readfirstlane((int)(gt >> 6));
    int d = threadIdx.x & 63;
    if (w >= nrows) return;
    int s = row_ptr[w], e = row_ptr[w + 1];
    float acc = 0.0f;
    for (int j = s; j < e; j += 16) {
#pragma unroll
        for (int k = 0; k < 16; k++) {
            int jj = j + k;
            bool live = jj < e;
            int2 pr = ev[live ? jj : s];                 // scalar (uniform) load
            float nn = live ? __int_as_float(pr.y) : 0.0f;
            unsigned off = (unsigned)pr.x + (unsigned)d; // 32-bit offset, SGPR base
            acc += bf2f(x[off]) * nn;
        }
    }
    out[(ll)w * 64 + d] = f2bf(acc * rnorm[w]);
}

// ---------------- fast tanh ----------
__device__ __forceinline__ float fast_tanh(float x) {
    return 1.0f - 2.0f / (__expf(2.0f * x) + 1.0f);
}

// ---------------- MFMA semantic-attention scores ----------------
__global__ __launch_bounds__(256) void k_attn_mfma(const ushort_t* __restrict__ z1,
                                                   const ushort_t* __restrict__ z2,
                                                   const ushort_t* __restrict__ Wb,
                                                   const float* __restrict__ b1f,
                                                   const float* __restrict__ w2f,
                                                   const int n, float* __restrict__ wsum) {
    __shared__ float red0[4], red1[4];
    int tid = threadIdx.x;
    int lane = tid & 63;
    int wid = tid >> 6;
    int col = lane & 15;
    int quad = lane >> 4;

    bf16x8 wb[8][2];
#pragma unroll
    for (int ht = 0; ht < 8; ht++) {
        int h = ht * 16 + col;
#pragma unroll
        for (int ks = 0; ks < 2; ks++) {
            wb[ht][ks] = *(const bf16x8*)&Wb[h * 64 + ks * 32 + quad * 8];
        }
    }
    float b1v[8], w2v[8];
#pragma unroll
    for (int ht = 0; ht < 8; ht++) {
        b1v[ht] = b1f[ht * 16 + col];
        w2v[ht] = w2f[ht * 16 + col];
    }

    float w0 = 0.0f, w1 = 0.0f;
    int ntiles = (n + 15) >> 4;
    int gw = blockIdx.x * 4 + wid;
    int nw = gridDim.x * 4;
    const bf16x8 zero8 = {0, 0, 0, 0, 0, 0, 0, 0};

    for (int tile = gw; tile < ntiles; tile += nw) {
        int nodeA = tile * 16 + col;
        bool va = nodeA < n;
        bf16x8 a1[2], a2[2];
#pragma unroll
        for (int ks = 0; ks < 2; ks++) {
            const bf16x8* p1 = (const bf16x8*)&z1[(ll)nodeA * 64 + ks * 32 + quad * 8];
            const bf16x8* p2 = (const bf16x8*)&z2[(ll)nodeA * 64 + ks * 32 + quad * 8];
            a1[ks] = va ? p1[0] : zero8;
            a2[ks] = va ? p2[0] : zero8;
        }
#pragma unroll
        for (int ht = 0; ht < 8; ht++) {
            f32x4 c1 = {0.f, 0.f, 0.f, 0.f};
            f32x4 c2 = {0.f, 0.f, 0.f, 0.f};
            c1 = __builtin_amdgcn_mfma_f32_16x16x32_bf16(a1[0], wb[ht][0], c1, 0, 0, 0);
            c1 = __builtin_amdgcn_mfma_f32_16x16x32_bf16(a1[1], wb[ht][1], c1, 0, 0, 0);
            c2 = __builtin_amdgcn_mfma_f32_16x16x32_bf16(a2[0], wb[ht][0], c2, 0, 0, 0);
            c2 = __builtin_amdgcn_mfma_f32_16x16x32_bf16(a2[1], wb[ht][1], c2, 0, 0, 0);
#pragma unroll
            for (int r = 0; r < 4; r++) {
                int node_row = tile * 16 + quad * 4 + r;
                bool vr = node_row < n;
                float t1 = fast_tanh(c1[r] + b1v[ht]) * w2v[ht];
                float t2 = fast_tanh(c2[r] + b1v[ht]) * w2v[ht];
                w0 += vr ? t1 : 0.0f;
                w1 += vr ? t2 : 0.0f;
            }
        }
    }

    for (int off = 32; off > 0; off >>= 1) {
        w0 += __shfl_down(w0, off);
        w1 += __shfl_down(w1, off);
    }
    if (lane == 0) { red0[wid] = w0; red1[wid] = w1; }
    __syncthreads();
    if (tid == 0) {
        atomicAdd(&wsum[0], red0[0] + red0[1] + red0[2] + red0[3]);
        atomicAdd(&wsum[1], red1[0] + red1[1] + red1[2] + red1[3]);
    }
}

// ---------------- combine with inline beta softmax (bf16 in/out) ----------
__global__ void k_combine(const ushort_t* __restrict__ z1, const ushort_t* __restrict__ z2,
                          const float* __restrict__ wsum, const float inv_n,
                          ushort_t* __restrict__ h, const ll n64) {
    ll t = (ll)blockIdx.x * blockDim.x + threadIdx.x;
    if (t < n64) {
        float m0 = wsum[0] * inv_n, m1 = wsum[1] * inv_n;
        float mx = fmaxf(m0, m1);
        float e0 = __expf(m0 - mx), e1 = __expf(m1 - mx);
        float inv_s = 1.0f / (e0 + e1);
        h[t] = f2bf((e0 * bf2f(z1[t]) + e1 * bf2f(z2[t])) * inv_s);
    }
}

// ---------------- fused output gather ----------------
__device__ __forceinline__ void store_out(void* out, ll i, float v, int isbf16) {
    if (isbf16) ((ushort_t*)out)[i] = f2bf(v);
    else ((float*)out)[i] = v;
}

__global__ void k_out(const ushort_t* __restrict__ hu, const ushort_t* __restrict__ hi,
                      const ushort_t* __restrict__ ui, const int* __restrict__ user_idx,
                      const int* __restrict__ item_idx, const int* __restrict__ neg_idx,
                      void* __restrict__ out, const int B, const ll U,
                      const int* __restrict__ flag) {
    ll t = (ll)blockIdx.x * blockDim.x + threadIdx.x;
    int bf = *flag;
    int d = (int)(t & 63);
    ll b = t >> 6;
    if (b < B) {
        int u = user_idx[b];
        float v = 0.5f * bf2f(hu[(ll)u * 64 + d]) + 0.5f * bf2f(ui[(ll)u * 64 + d]);
        store_out(out, b * 64 + d, v, bf);
    } else if (b < 2 * (ll)B) {
        ll bb = b - B;
        int it = item_idx[bb];
        float v = 0.5f * bf2f(hi[(ll)it * 64 + d]) + 0.5f * bf2f(ui[(U + it) * 64 + d]);
        store_out(out, (ll)B * 64 + bb * 64 + d, v, bf);
    } else if (b < 3 * (ll)B) {
        ll bb = b - 2 * (ll)B;
        int it = item_idx[neg_idx[bb]];
        float v = 0.5f * bf2f(hi[(ll)it * 64 + d]) + 0.5f * bf2f(ui[(U + it) * 64 + d]);
        store_out(out, (ll)2 * B * 64 + bb * 64 + d, v, bf);
    }
}

extern "C" void kernel_launch(void* const* d_in, const int* in_sizes, int n_in,
                              void* d_out, int out_size, void* d_ws, size_t ws_size,
                              hipStream_t stream) {
    const int D = 64;
    const ll U = in_sizes[0] / D;
    const ll I = in_sizes[1] / D;
    const ll N = U + I;
    const ll E2  = in_sizes[8] / 2;
    const ll EU1 = in_sizes[9] / 2;
    const ll EU2 = in_sizes[10] / 2;
    const ll EI1 = in_sizes[11] / 2;
    const ll EI2 = in_sizes[12] / 2;
    const ll ET = E2 + EU1 + EU2 + EI1 + EI2;
    const ll RT = E2 + 2 * (EU1 + EU2 + EI1 + EI2);   // binning records
    const int B = in_sizes[13];
    const int M = (int)(N + 2 * U + 2 * I);           // CSR/in-deg index space
    const int M2 = (int)(N + 4 * U + 4 * I);          // + out-deg space
    const int K = (M2 + BIN_SIZE - 1) >> BIN_SHIFT;   // buckets
    const int KM = (M + BIN_SIZE - 1) >> BIN_SHIFT;   // buckets covering [0,M)
    if (K > KMAX) return;

    const void* user_feat = d_in[0];
    const void* item_feat = d_in[1];
    const int* uiR = (const int*)d_in[8];
    const int* uiC = uiR + E2;
    const int* u1s = (const int*)d_in[9];
    const int* u1d = u1s + EU1;
    const int* u2s = (const int*)d_in[10];
    const int* u2d = u2s + EU2;
    const int* i1s = (const int*)d_in[11];
    const int* i1d = i1s + EI1;
    const int* i2s = (const int*)d_in[12];
    const int* i2d = i2s + EI2;
    const int* user_idx = (const int*)d_in[13];
    const int* item_idx = (const int*)d_in[14];
    const int* neg_idx  = (const int*)d_in[15];

    const int T = 256;
    // ~252 WGs of 16 waves each; chunk rounded up to BT multiple.
    const ll CHUNKD = ((RT + 251) / 252 + (ll)BT - 1) / (ll)BT * (ll)BT;
    const int nWG_A = cdiv_ll(RT, CHUNKD);

    // ---------------- workspace layout ----------------
    ushort_t* q = (ushort_t*)d_ws;
    ushort_t* ui0 = q; q += N * 64;
    ushort_t* ui1 = q; q += N * 64;
    ushort_t* z1  = q; q += I * 64;
    ushort_t* z2  = q; q += I * 64;
    ushort_t* hu  = q; q += U * 64;
    ushort_t* hi  = q; q += I * 64;
    size_t feat_bytes = (size_t)(q - (ushort_t*)d_ws) * 2;
    if (feat_bytes < (size_t)RT * 4) return;   // binned overlay must fit (4B records)
    unsigned* binned = (unsigned*)d_ws;

    float* p = (float*)(((uintptr_t)q + 15) & ~(uintptr_t)15);
    float* nrm = p;  p += M2;
    ushort_t* Wbu = (ushort_t*)p; p += 64 * 128 / 2;
    ushort_t* Wbi = (ushort_t*)p; p += 64 * 128 / 2;
    float* wb1u = p; p += 128;
    float* ww2u = p; p += 128;
    float* wb1i = p; p += 128;
    float* ww2i = p; p += 128;
    float* scratch = p; p += 16;

    int* ip = (int*)p;
    int* btot = ip;    ip += KMAX * 32;
    int* bbase = ip;   ip += KMAX;
    int* bcursor = ip; ip += KMAX * 32;
    int* counts = ip;  ip += M2;
    int* S = ip;       ip += M + 1;
    ip = (int*)(((uintptr_t)ip + 7) & ~(uintptr_t)7);
    int2* ev_all = (int2*)ip; ip += 2 * ET;           // fused (col*64, norm) payload
    int* whist = ip;   ip += (size_t)nWG_A * K;       // per-WG bucket histograms
    int* bsum = ip;    ip += 256;
    int* flag = ip;    ip += 4;
    size_t needed = (size_t)((char*)ip - (char*)d_ws);
    if (ws_size < needed) return;

    // ---------------- dtype detection + weight conversion ----------------
    k_detect<<<1, 256, 0, stream>>>((const unsigned int*)user_feat, (ll)in_sizes[0] / 2, flag);
    k_cvt_weights<<<cdiv_ll(2 * (64 * 128 + 256), T), T, 0, stream>>>(
        d_in[2], d_in[3], d_in[4], d_in[5], d_in[6], d_in[7],
        Wbu, wb1u, ww2u, Wbi, wb1i, ww2i, flag);

    // ---------------- CSR build via 2-level binning ----------------
    hipMemsetAsync(btot, 0, (size_t)KMAX * 32 * sizeof(int), stream);
    hipMemsetAsync(scratch, 0, 16 * sizeof(float), stream);
    kA_hist<<<nWG_A, BT, 0, stream>>>(uiR, u1s, u1d, u2s, u2d, i1s, i1d, i2s, i2d,
                                      E2, EU1, EU2, EI1, EI2, (int)N, (int)U, (int)I, M,
                                      RT, CHUNKD, K, btot, whist);
    k_bscan<<<1, 1024, 0, stream>>>(btot, bbase, bcursor, K);
    kA_scatter<<<nWG_A, BT, 0, stream>>>(uiR, uiC, u1s, u1d, u2s, u2d, i1s, i1d, i2s, i2d,
                                         E2, EU1, EU2, EI1, EI2, (int)N, (int)U, (int)I, M,
                                         RT, CHUNKD, K, bcursor, whist, binned);
    kB1_count<<<K, T, 0, stream>>>(binned, bbase, btot, counts, M2);
    k_norm_all<<<cdiv_ll(M2, T), T, 0, stream>>>(counts, nrm, (int)N, M2);
    {
        int nb = (M + SCAN_CHUNK - 1) / SCAN_CHUNK;
        k_scanA<<<nb, SCAN_T, 0, stream>>>(counts, M, S, bsum);
        k_scanB<<<1, 256, 0, stream>>>(bsum, nb);
        k_scanC<<<cdiv_ll(M, T), T, 0, stream>>>(S, M, bsum, (int)ET);
    }
    kB2_fill<<<KM, T, 0, stream>>>(binned, bbase, btot, S, nrm,
                                   (int)N, (int)U, (int)I, M, ev_all);

    // ---------------- init features (after binned is consumed) ----------------
    k_init<<<cdiv_ll(N * 64, T), T, 0, stream>>>(user_feat, item_feat, ui0, hu, hi, U * 64, N * 64, flag);

    // CSR segment row_ptr views
    const int* rp_ui = S;
    const int* rp_u1 = S + N;
    const int* rp_u2 = S + N + U;
    const int* rp_i1 = S + N + 2 * U;
    const int* rp_i2 = S + N + 2 * U + I;
    // row-norm views (col-norms live in the fused edge payload)
    const float* dinv = nrm;
    const float* n_u1r = nrm + N;          const float* n_u2r = nrm + N + U;
    const float* n_i1r = nrm + N + 2 * U;  const float* n_i2r = nrm + N + 2 * U + I;

    ushort_t* uiA = ui0;
    ushort_t* uiB = ui1;
    const int ATTN_BLOCKS = 512;

    for (int layer = 0; layer < 2; layer++) {
        float* wsU = scratch + (layer ? 8 : 0);
        float* wsI = scratch + (layer ? 12 : 4);

        // ---- gcn_spmm ----
        k_gather<<<cdiv_ll(N * 64, T), T, 0, stream>>>(rp_ui, ev_all, uiA, dinv, uiB, (int)N);
        { ushort_t* tmp = uiA; uiA = uiB; uiB = tmp; }

        // ---- HAN: users ----
        k_gather<<<cdiv_ll(U * 64, T), T, 0, stream>>>(rp_u1, ev_all, hu, n_u1r, z1, (int)U);
        k_gather<<<cdiv_ll(U * 64, T), T, 0, stream>>>(rp_u2, ev_all, hu, n_u2r, z2, (int)U);
        k_attn_mfma<<<ATTN_BLOCKS, T, 0, stream>>>(z1, z2, Wbu, wb1u, ww2u, (int)U, wsU);
        k_combine<<<cdiv_ll(U * 64, T), T, 0, stream>>>(z1, z2, wsU, 1.0f / (float)U, hu, U * 64);

        // ---- HAN: items ----
        k_gather<<<cdiv_ll(I * 64, T), T, 0, stream>>>(rp_i1, ev_all, hi, n_i1r, z1, (int)I);
        k_gather<<<cdiv_ll(I * 64, T), T, 0, stream>>>(rp_i2, ev_all, hi, n_i2r, z2, (int)I);
        k_attn_mfma<<<ATTN_BLOCKS, T, 0, stream>>>(z1, z2, Wbi, wb1i, ww2i, (int)I, wsI);
        k_combine<<<cdiv_ll(I * 64, T), T, 0, stream>>>(z1, z2, wsI, 1.0f / (float)I, hi, I * 64);
    }

    // ---------------- final ----------------
    k_out<<<cdiv_ll((ll)3 * B * 64, T), T, 0, stream>>>(hu, hi, uiA, user_idx, item_idx, neg_idx,
                                                        d_out, B, U, flag);
}

// Round 9
// 838.058 us; speedup vs baseline: 1.0417x; 1.0417x over previous
//
#include <hip/hip_runtime.h>
#include <hip/hip_bf16.h>
#include <stdint.h>

typedef long long ll;
typedef unsigned short ushort_t;
typedef __attribute__((ext_vector_type(8))) short bf16x8;
typedef __attribute__((ext_vector_type(4))) float f32x4;

static inline int cdiv_ll(ll a, ll b) { return (int)((a + b - 1) / b); }

#define BIN_SHIFT 8
#define BIN_SIZE 256
#define KMAX 3072         // max buckets over M2 (M2 <= 786K)
#define BT 1024           // binning block threads (16 waves)
#define FILL_CAP 7936     // staged edges per bucket (63.5 KB LDS)

// ---------------- dtype detection (bf16 vs fp32 inputs) ----------------
__global__ void k_detect(const unsigned int* __restrict__ dw, const ll n_dw, int* __restrict__ flag) {
    __shared__ int sc[256];
    int tid = threadIdx.x;
    int cnt = 0;
    for (int s = 0; s < 32; s++) {
        ll idx = (ll)(s * 256 + tid);
        ll i = (idx * n_dw) / 8192;
        unsigned v = dw[i];
        unsigned lo = v & 0xFFFFu;
        unsigned ex = (lo >> 7) & 0xFFu;
        bool pl = (lo == 0u) || (lo == 0x8000u) || (ex >= 0x60u && ex <= 0x8Fu);
        cnt += pl ? 1 : 0;
    }
    sc[tid] = cnt;
    __syncthreads();
    for (int o = 128; o > 0; o >>= 1) { if (tid < o) sc[tid] += sc[tid + o]; __syncthreads(); }
    if (tid == 0) *flag = (sc[0] * 2 > 8192) ? 1 : 0;
}

__device__ __forceinline__ float load_in(const void* p, ll i, int isbf16) {
    if (isbf16) return __bfloat162float(((const __hip_bfloat16*)p)[i]);
    return ((const float*)p)[i];
}

__device__ __forceinline__ float bf2f(ushort_t u) {
    return __uint_as_float(((unsigned)u) << 16);
}
__device__ __forceinline__ ushort_t f2bf(float f) {
    unsigned u = __float_as_uint(f);
    unsigned r = (u + 0x7FFFu + ((u >> 16) & 1u)) >> 16;
    return (ushort_t)r;
}

// ---------------- fused weight conversion ----------------
__global__ void k_cvt_weights(const void* __restrict__ W1u, const void* __restrict__ b1u,
                              const void* __restrict__ w2u, const void* __restrict__ W1i,
                              const void* __restrict__ b1i, const void* __restrict__ w2i,
                              ushort_t* __restrict__ Wbu, float* __restrict__ fb1u,
                              float* __restrict__ fw2u, ushort_t* __restrict__ Wbi,
                              float* __restrict__ fb1i, float* __restrict__ fw2i,
                              const int* __restrict__ flag) {
    int i = blockIdx.x * blockDim.x + threadIdx.x;
    int bf = *flag;
    const int WSZ = 64 * 128;
    if (i < WSZ) {
        int d = i >> 7, h = i & 127;
        Wbu[h * 64 + d] = f2bf(load_in(W1u, i, bf));
    } else if (i < WSZ + 128) {
        fb1u[i - WSZ] = load_in(b1u, i - WSZ, bf);
    } else if (i < WSZ + 256) {
        fw2u[i - WSZ - 128] = load_in(w2u, i - WSZ - 128, bf);
    } else if (i < 2 * WSZ + 256) {
        int j = i - WSZ - 256;
        int d = j >> 7, h = j & 127;
        Wbi[h * 64 + d] = f2bf(load_in(W1i, j, bf));
    } else if (i < 2 * WSZ + 384) {
        fb1i[i - 2 * WSZ - 256] = load_in(b1i, i - 2 * WSZ - 256, bf);
    } else if (i < 2 * WSZ + 512) {
        fw2i[i - 2 * WSZ - 384] = load_in(w2i, i - 2 * WSZ - 384, bf);
    }
}

// ---------------- record decode (in-CSR + out-deg records, M2 keyspace) ----
__device__ __forceinline__ void decode_rec(ll t,
    const int* __restrict__ uiR, const int* __restrict__ uiC,
    const int* __restrict__ u1s, const int* __restrict__ u1d,
    const int* __restrict__ u2s, const int* __restrict__ u2d,
    const int* __restrict__ i1s, const int* __restrict__ i1d,
    const int* __restrict__ i2s, const int* __restrict__ i2d,
    const ll E2, const ll EU1, const ll EU2, const ll EI1, const ll EI2,
    const int N, const int U, const int I, const int M,
    int& key, int& col) {
    if (t < E2) { key = uiR[t]; col = uiC[t]; return; }
    t -= E2;
    if (t < EU1) { key = N + u1d[t]; col = u1s[t]; return; }
    t -= EU1;
    if (t < EU1) { key = M + u1s[t]; col = 0; return; }
    t -= EU1;
    if (t < EU2) { key = N + U + u2d[t]; col = u2s[t]; return; }
    t -= EU2;
    if (t < EU2) { key = M + U + u2s[t]; col = 0; return; }
    t -= EU2;
    if (t < EI1) { key = N + 2 * U + i1d[t]; col = i1s[t]; return; }
    t -= EI1;
    if (t < EI1) { key = M + 2 * U + i1s[t]; col = 0; return; }
    t -= EI1;
    if (t < EI2) { key = N + 2 * U + I + i2d[t]; col = i2s[t]; return; }
    t -= EI2;
    key = M + 2 * U + I + i2s[t]; col = 0;
}

// key-only decode (histogram pass never needs col)
__device__ __forceinline__ int decode_key(ll t,
    const int* __restrict__ uiR,
    const int* __restrict__ u1s, const int* __restrict__ u1d,
    const int* __restrict__ u2s, const int* __restrict__ u2d,
    const int* __restrict__ i1s, const int* __restrict__ i1d,
    const int* __restrict__ i2s, const int* __restrict__ i2d,
    const ll E2, const ll EU1, const ll EU2, const ll EI1, const ll EI2,
    const int N, const int U, const int I, const int M) {
    if (t < E2) return uiR[t];
    t -= E2;
    if (t < EU1) return N + u1d[t];
    t -= EU1;
    if (t < EU1) return M + u1s[t];
    t -= EU1;
    if (t < EU2) return N + U + u2d[t];
    t -= EU2;
    if (t < EU2) return M + U + u2s[t];
    t -= EU2;
    if (t < EI1) return N + 2 * U + i1d[t];
    t -= EI1;
    if (t < EI1) return M + 2 * U + i1s[t];
    t -= EI1;
    if (t < EI2) return N + 2 * U + I + i2d[t];
    t -= EI2;
    return M + 2 * U + I + i2s[t];
}

#define DECODE_ARGS uiR, uiC, u1s, u1d, u2s, u2d, i1s, i1d, i2s, i2d, \
                    E2, EU1, EU2, EI1, EI2, N, U, I, M

// ---------------- pass A1: per-WG LDS histogram ----------------
__global__ __launch_bounds__(BT) void kA_hist(
    const int* __restrict__ uiR,
    const int* __restrict__ u1s, const int* __restrict__ u1d,
    const int* __restrict__ u2s, const int* __restrict__ u2d,
    const int* __restrict__ i1s, const int* __restrict__ i1d,
    const int* __restrict__ i2s, const int* __restrict__ i2d,
    const ll E2, const ll EU1, const ll EU2, const ll EI1, const ll EI2,
    const int N, const int U, const int I, const int M,
    const ll RT, const ll CHUNKD, const int K,
    int* __restrict__ btot /* K*32 line-padded */,
    int* __restrict__ whist /* nWG x K */) {
    __shared__ int hist[KMAX];
    for (int i = threadIdx.x; i < K; i += BT) hist[i] = 0;
    __syncthreads();
    ll base = (ll)blockIdx.x * CHUNKD;
    ll lim = base + CHUNKD;
    if (lim > RT) lim = RT;
    for (ll t = base + threadIdx.x; t < lim; t += BT) {
        int key = decode_key(t, uiR, u1s, u1d, u2s, u2d, i1s, i1d, i2s, i2d,
                             E2, EU1, EU2, EI1, EI2, N, U, I, M);
        atomicAdd(&hist[key >> BIN_SHIFT], 1);
    }
    __syncthreads();
    ll wb = (ll)blockIdx.x * K;
    for (int k = threadIdx.x; k < K; k += BT) {
        int h = hist[k];
        whist[wb + k] = h;
        if (h) atomicAdd(&btot[k * 32], h);
    }
}

// ---------------- bucket scan: totals -> bases, init cursors ----------------
__global__ __launch_bounds__(1024) void k_bscan(const int* __restrict__ btot,
                                                int* __restrict__ bbase,
                                                int* __restrict__ bcursor, const int K) {
    __shared__ int sh[1024];
    __shared__ int carry;
    int t = threadIdx.x;
    if (t == 0) carry = 0;
    __syncthreads();
    for (int base = 0; base < K; base += 1024) {
        int idx = base + t;
        int v = (idx < K) ? btot[idx * 32] : 0;
        sh[t] = v;
        __syncthreads();
        for (int off = 1; off < 1024; off <<= 1) {
            int x = (t >= off) ? sh[t - off] : 0;
            __syncthreads();
            sh[t] += x;
            __syncthreads();
        }
        if (idx < K) {
            int ex = carry + sh[t] - v;
            bbase[idx] = ex;
            bcursor[idx * 32] = ex;
        }
        __syncthreads();
        if (t == 0) carry += sh[1023];
        __syncthreads();
    }
}

// ---------------- pass A2: scatter (single decode pass) -------
__global__ __launch_bounds__(BT) void kA_scatter(
    const int* __restrict__ uiR, const int* __restrict__ uiC,
    const int* __restrict__ u1s, const int* __restrict__ u1d,
    const int* __restrict__ u2s, const int* __restrict__ u2d,
    const int* __restrict__ i1s, const int* __restrict__ i1d,
    const int* __restrict__ i2s, const int* __restrict__ i2d,
    const ll E2, const ll EU1, const ll EU2, const ll EI1, const ll EI2,
    const int N, const int U, const int I, const int M,
    const ll RT, const ll CHUNKD, const int K, int* __restrict__ bcursor,
    const int* __restrict__ whist,
    unsigned* __restrict__ binned) {
    __shared__ int lcur[KMAX];
    ll wb = (ll)blockIdx.x * K;
    for (int k = threadIdx.x; k < K; k += BT) {
        int h = whist[wb + k];
        lcur[k] = h ? atomicAdd(&bcursor[k * 32], h) : 0;
    }
    __syncthreads();
    ll base = (ll)blockIdx.x * CHUNKD;
    ll lim = base + CHUNKD;
    if (lim > RT) lim = RT;
    for (ll t = base + threadIdx.x; t < lim; t += BT) {
        int key, col;
        decode_rec(t, DECODE_ARGS, key, col);
        int pos = atomicAdd(&lcur[key >> BIN_SHIFT], 1);
        binned[pos] = ((unsigned)(key & 255) << 24) | (unsigned)col;
    }
}

// ---------------- pass B1: per-bucket LDS count -> counts array ----------
__global__ __launch_bounds__(256) void kB1_count(const unsigned* __restrict__ binned,
                                                 const int* __restrict__ bbase,
                                                 const int* __restrict__ btot,
                                                 int* __restrict__ counts, const int M2) {
    __shared__ int cnt[BIN_SIZE];
    int b = blockIdx.x;
    int lo = b << BIN_SHIFT;
    int hi = min(lo + BIN_SIZE, M2);
    for (int i = threadIdx.x; i < BIN_SIZE; i += 256) cnt[i] = 0;
    __syncthreads();
    int s = bbase[b], n = btot[b * 32];
    for (int j = s + threadIdx.x; j < s + n; j += 256) {
        atomicAdd(&cnt[binned[j] >> 24], 1);
    }
    __syncthreads();
    for (int i = threadIdx.x; i < hi - lo; i += 256) counts[lo + i] = cnt[i];
}

// ---------------- fused norms ----------------
__global__ void k_norm_all(const int* __restrict__ counts, float* __restrict__ nrm,
                           const int N, const int total) {
    int i = blockIdx.x * blockDim.x + threadIdx.x;
    if (i < total) {
        int c = counts[i];
        if (i < N) nrm[i] = (c > 0) ? (1.0f / sqrtf((float)c)) : 0.0f;
        else nrm[i] = 1.0f / sqrtf(fmaxf((float)c, 1.0f));
    }
}

// ---------------- hierarchical exclusive scan ----------
#define SCAN_T 256
#define SCAN_ELEMS 8
#define SCAN_CHUNK (SCAN_T * SCAN_ELEMS)   // 2048

__global__ __launch_bounds__(256) void k_scanA(const int* __restrict__ in, const int n,
                                               int* __restrict__ out, int* __restrict__ bsum) {
    __shared__ int sh[SCAN_T];
    int t = threadIdx.x;
    ll base = (ll)blockIdx.x * SCAN_CHUNK + (ll)t * SCAN_ELEMS;
    int v[SCAN_ELEMS];
    int tot = 0;
#pragma unroll
    for (int k = 0; k < SCAN_ELEMS; k++) {
        ll i = base + k;
        v[k] = (i < n) ? in[i] : 0;
        tot += v[k];
    }
    sh[t] = tot;
    __syncthreads();
    for (int off = 1; off < SCAN_T; off <<= 1) {
        int x = (t >= off) ? sh[t - off] : 0;
        __syncthreads();
        sh[t] += x;
        __syncthreads();
    }
    int run = sh[t] - tot;
#pragma unroll
    for (int k = 0; k < SCAN_ELEMS; k++) {
        ll i = base + k;
        if (i < n) out[i] = run;
        run += v[k];
    }
    if (t == SCAN_T - 1) bsum[blockIdx.x] = sh[SCAN_T - 1];
}

__global__ __launch_bounds__(256) void k_scanB(int* __restrict__ bsum, const int nb) {
    __shared__ int sh[256];
    int t = threadIdx.x;
    int running = 0;
    for (int base = 0; base < nb; base += 256) {
        int idx = base + t;
        int v = (idx < nb) ? bsum[idx] : 0;
        sh[t] = v;
        __syncthreads();
        for (int off = 1; off < 256; off <<= 1) {
            int x = (t >= off) ? sh[t - off] : 0;
            __syncthreads();
            sh[t] += x;
            __syncthreads();
        }
        if (idx < nb) bsum[idx] = running + sh[t] - v;
        int tot = sh[255];
        __syncthreads();
        running += tot;
    }
}

__global__ void k_scanC(int* __restrict__ S, const int n, const int* __restrict__ bsum, const int ET) {
    ll i = (ll)blockIdx.x * blockDim.x + threadIdx.x;
    if (i < n) S[i] += bsum[i / SCAN_CHUNK];
    if (i == 0) S[n] = ET;
}

// ---------------- pass B2: per-bucket CSR fill, LDS-staged ----------
__global__ __launch_bounds__(256) void kB2_fill(const unsigned* __restrict__ binned,
                                                const int* __restrict__ bbase,
                                                const int* __restrict__ btot,
                                                const int* __restrict__ S,
                                                const float* __restrict__ nrm,
                                                const int N, const int U, const int I,
                                                const int M,
                                                int2* __restrict__ ev_all) {
    __shared__ int scur[BIN_SIZE];
    __shared__ int2 buf[FILL_CAP];
    int b = blockIdx.x;
    int lo = b << BIN_SHIFT;
    int hi = min(lo + BIN_SIZE, M);
    int obase = S[lo];
    int nfill = S[hi] - obase;
    int s = bbase[b], n = btot[b * 32];
    const int segU = N + U, seg2U = N + 2 * U, segI = N + 2 * U + I;
    if (n <= FILL_CAP) {
        for (int i = threadIdx.x; i < hi - lo; i += 256) scur[i] = S[lo + i] - obase;
        __syncthreads();
        for (int j = s + threadIdx.x; j < s + n; j += 256) {
            unsigned rec = binned[j];
            int key = lo + (int)(rec >> 24);
            if (key < M) {
                int pos = atomicAdd(&scur[key - lo], 1);
                int col = (int)(rec & 0xFFFFFFu);
                int nidx;
                if (key < N)          nidx = col;                   // ui: dinv[col]
                else if (key < segU)  nidx = M + col;               // u1 src out-deg norm
                else if (key < seg2U) nidx = M + U + col;           // u2
                else if (key < segI)  nidx = M + 2 * U + col;       // i1
                else                  nidx = M + 2 * U + I + col;   // i2
                buf[pos] = make_int2(col * 64, __float_as_int(nrm[nidx]));
            }
        }
        __syncthreads();
        for (int i = threadIdx.x; i < nfill; i += 256)
            ev_all[obase + i] = buf[i];
    } else {
        // fallback: direct scatter (correct for any bucket size)
        for (int i = threadIdx.x; i < hi - lo; i += 256) scur[i] = S[lo + i];
        __syncthreads();
        for (int j = s + threadIdx.x; j < s + n; j += 256) {
            unsigned rec = binned[j];
            int key = lo + (int)(rec >> 24);
            if (key < M) {
                int pos = atomicAdd(&scur[key - lo], 1);
                int col = (int)(rec & 0xFFFFFFu);
                int nidx;
                if (key < N)          nidx = col;
                else if (key < segU)  nidx = M + col;
                else if (key < seg2U) nidx = M + U + col;
                else if (key < segI)  nidx = M + 2 * U + col;
                else                  nidx = M + 2 * U + I + col;
                ev_all[pos] = make_int2(col * 64, __float_as_int(nrm[nidx]));
            }
        }
    }
}

// ---------------- init features (bf16 storage) ----------------
__global__ void k_init(const void* __restrict__ uf, const void* __restrict__ itf,
                       ushort_t* __restrict__ ui, ushort_t* __restrict__ hu,
                       ushort_t* __restrict__ hi,
                       const ll nu64, const ll ntot64, const int* __restrict__ flag) {
    ll t = (ll)blockIdx.x * blockDim.x + threadIdx.x;
    int bf = *flag;
    if (t < nu64) {
        ushort_t v = bf ? ((const ushort_t*)uf)[t] : f2bf(((const float*)uf)[t]);
        ui[t] = v; hu[t] = v;
    } else if (t < ntot64) {
        ll j = t - nu64;
        ushort_t v = bf ? ((const ushort_t*)itf)[j] : f2bf(((const float*)itf)[j]);
        ui[t] = v; hi[j] = v;
    }
}

// ---------------- fused 5-segment gather SpMM ----------------
// All five per-layer SpMMs are independent (ui: uiA->uiB; u1,u2: hu->zu*;
// i1,i2: hi->zi*), and S is the row_ptr over all M rows in exactly this
// segment order with nrm[w] the matching row-norm. One kernel overlaps the
// latency-bound small gathers under the big ones and drops 8 launch gaps.
__global__ __launch_bounds__(256) void k_gather5(const int* __restrict__ S,
                                                 const int2* __restrict__ ev,
                                                 const float* __restrict__ nrm,
                                                 const ushort_t* __restrict__ xui,
                                                 const ushort_t* __restrict__ xu,
                                                 const ushort_t* __restrict__ xi,
                                                 ushort_t* __restrict__ out_ui,
                                                 ushort_t* __restrict__ o_zu1,
                                                 ushort_t* __restrict__ o_zu2,
                                                 ushort_t* __restrict__ o_zi1,
                                                 ushort_t* __restrict__ o_zi2,
                                                 const int N, const int U, const int I,
                                                 const int M) {
    ll gt = (ll)blockIdx.x * blockDim.x + threadIdx.x;
    int w = __builtin_amdgcn_readfirstlane((int)(gt >> 6));
    int d = threadIdx.x & 63;
    if (w >= M) return;
    const ushort_t* x;
    ushort_t* out;
    int orow;
    if (w < N)              { x = xui; out = out_ui; orow = w; }
    else if (w < N + U)     { x = xu;  out = o_zu1;  orow = w - N; }
    else if (w < N + 2 * U) { x = xu;  out = o_zu2;  orow = w - N - U; }
    else if (w < N + 2 * U + I) { x = xi; out = o_zi1; orow = w - N - 2 * U; }
    else                    { x = xi;  out = o_zi2;  orow = w - N - 2 * U - I; }
    int s = S[w], e = S[w + 1];
    float acc = 0.0f;
    for (int j = s; j < e; j += 16) {
#pragma unroll
        for (int k = 0; k < 16; k++) {
            int jj = j + k;
            bool live = jj < e;
            int2 pr = ev[live ? jj : s];                 // scalar (uniform) load
            float nn = live ? __int_as_float(pr.y) : 0.0f;
            unsigned off = (unsigned)pr.x + (unsigned)d; // 32-bit offset, SGPR base
            acc += bf2f(x[off]) * nn;
        }
    }
    out[(ll)orow * 64 + d] = f2bf(acc * nrm[w]);
}

// ---------------- fast tanh ----------
__device__ __forceinline__ float fast_tanh(float x) {
    return 1.0f - 2.0f / (__expf(2.0f * x) + 1.0f);
}

// ---------------- MFMA semantic-attention scores, fused U+I halves --------
__global__ __launch_bounds__(256) void k_attn2(const ushort_t* __restrict__ zu1,
                                               const ushort_t* __restrict__ zu2,
                                               const ushort_t* __restrict__ Wbu,
                                               const float* __restrict__ b1u,
                                               const float* __restrict__ w2u,
                                               const int nU, float* __restrict__ wsU,
                                               const ushort_t* __restrict__ zi1,
                                               const ushort_t* __restrict__ zi2,
                                               const ushort_t* __restrict__ Wbi,
                                               const float* __restrict__ b1f_i,
                                               const float* __restrict__ w2f_i,
                                               const int nI, float* __restrict__ wsI,
                                               const int half) {
    __shared__ float red0[4], red1[4];
    bool isU = (int)blockIdx.x < half;
    const ushort_t* z1 = isU ? zu1 : zi1;
    const ushort_t* z2 = isU ? zu2 : zi2;
    const ushort_t* Wb = isU ? Wbu : Wbi;
    const float* b1f = isU ? b1u : b1f_i;
    const float* w2f = isU ? w2u : w2f_i;
    const int n = isU ? nU : nI;
    float* wsum = isU ? wsU : wsI;
    int blk = isU ? (int)blockIdx.x : (int)blockIdx.x - half;

    int tid = threadIdx.x;
    int lane = tid & 63;
    int wid = tid >> 6;
    int col = lane & 15;
    int quad = lane >> 4;

    bf16x8 wb[8][2];
#pragma unroll
    for (int ht = 0; ht < 8; ht++) {
        int h = ht * 16 + col;
#pragma unroll
        for (int ks = 0; ks < 2; ks++) {
            wb[ht][ks] = *(const bf16x8*)&Wb[h * 64 + ks * 32 + quad * 8];
        }
    }
    float b1v[8], w2v[8];
#pragma unroll
    for (int ht = 0; ht < 8; ht++) {
        b1v[ht] = b1f[ht * 16 + col];
        w2v[ht] = w2f[ht * 16 + col];
    }

    float w0 = 0.0f, w1 = 0.0f;
    int ntiles = (n + 15) >> 4;
    int gw = blk * 4 + wid;
    int nw = half * 4;
    const bf16x8 zero8 = {0, 0, 0, 0, 0, 0, 0, 0};

    for (int tile = gw; tile < ntiles; tile += nw) {
        int nodeA = tile * 16 + col;
        bool va = nodeA < n;
        bf16x8 a1[2], a2[2];
#pragma unroll
        for (int ks = 0; ks < 2; ks++) {
            const bf16x8* p1 = (const bf16x8*)&z1[(ll)nodeA * 64 + ks * 32 + quad * 8];
            const bf16x8* p2 = (const bf16x8*)&z2[(ll)nodeA * 64 + ks * 32 + quad * 8];
            a1[ks] = va ? p1[0] : zero8;
            a2[ks] = va ? p2[0] : zero8;
        }
#pragma unroll
        for (int ht = 0; ht < 8; ht++) {
            f32x4 c1 = {0.f, 0.f, 0.f, 0.f};
            f32x4 c2 = {0.f, 0.f, 0.f, 0.f};
            c1 = __builtin_amdgcn_mfma_f32_16x16x32_bf16(a1[0], wb[ht][0], c1, 0, 0, 0);
            c1 = __builtin_amdgcn_mfma_f32_16x16x32_bf16(a1[1], wb[ht][1], c1, 0, 0, 0);
            c2 = __builtin_amdgcn_mfma_f32_16x16x32_bf16(a2[0], wb[ht][0], c2, 0, 0, 0);
            c2 = __builtin_amdgcn_mfma_f32_16x16x32_bf16(a2[1], wb[ht][1], c2, 0, 0, 0);
#pragma unroll
            for (int r = 0; r < 4; r++) {
                int node_row = tile * 16 + quad * 4 + r;
                bool vr = node_row < n;
                float t1 = fast_tanh(c1[r] + b1v[ht]) * w2v[ht];
                float t2 = fast_tanh(c2[r] + b1v[ht]) * w2v[ht];
                w0 += vr ? t1 : 0.0f;
                w1 += vr ? t2 : 0.0f;
            }
        }
    }

    for (int off = 32; off > 0; off >>= 1) {
        w0 += __shfl_down(w0, off);
        w1 += __shfl_down(w1, off);
    }
    if (lane == 0) { red0[wid] = w0; red1[wid] = w1; }
    __syncthreads();
    if (tid == 0) {
        atomicAdd(&wsum[0], red0[0] + red0[1] + red0[2] + red0[3]);
        atomicAdd(&wsum[1], red1[0] + red1[1] + red1[2] + red1[3]);
    }
}

// ---------------- fused combine (U then I), inline beta softmax ----------
__global__ void k_combine2(const ushort_t* __restrict__ zu1, const ushort_t* __restrict__ zu2,
                           const float* __restrict__ wsU, const float inv_nU,
                           ushort_t* __restrict__ hu, const ll nu64,
                           const ushort_t* __restrict__ zi1, const ushort_t* __restrict__ zi2,
                           const float* __restrict__ wsI, const float inv_nI,
                           ushort_t* __restrict__ hi, const ll ntot64) {
    ll t = (ll)blockIdx.x * blockDim.x + threadIdx.x;
    if (t < nu64) {
        float m0 = wsU[0] * inv_nU, m1 = wsU[1] * inv_nU;
        float mx = fmaxf(m0, m1);
        float e0 = __expf(m0 - mx), e1 = __expf(m1 - mx);
        float inv_s = 1.0f / (e0 + e1);
        hu[t] = f2bf((e0 * bf2f(zu1[t]) + e1 * bf2f(zu2[t])) * inv_s);
    } else if (t < ntot64) {
        ll j = t - nu64;
        float m0 = wsI[0] * inv_nI, m1 = wsI[1] * inv_nI;
        float mx = fmaxf(m0, m1);
        float e0 = __expf(m0 - mx), e1 = __expf(m1 - mx);
        float inv_s = 1.0f / (e0 + e1);
        hi[j] = f2bf((e0 * bf2f(zi1[j]) + e1 * bf2f(zi2[j])) * inv_s);
    }
}

// ---------------- fused output gather ----------------
__device__ __forceinline__ void store_out(void* out, ll i, float v, int isbf16) {
    if (isbf16) ((ushort_t*)out)[i] = f2bf(v);
    else ((float*)out)[i] = v;
}

__global__ void k_out(const ushort_t* __restrict__ hu, const ushort_t* __restrict__ hi,
                      const ushort_t* __restrict__ ui, const int* __restrict__ user_idx,
                      const int* __restrict__ item_idx, const int* __restrict__ neg_idx,
                      void* __restrict__ out, const int B, const ll U,
                      const int* __restrict__ flag) {
    ll t = (ll)blockIdx.x * blockDim.x + threadIdx.x;
    int bf = *flag;
    int d = (int)(t & 63);
    ll b = t >> 6;
    if (b < B) {
        int u = user_idx[b];
        float v = 0.5f * bf2f(hu[(ll)u * 64 + d]) + 0.5f * bf2f(ui[(ll)u * 64 + d]);
        store_out(out, b * 64 + d, v, bf);
    } else if (b < 2 * (ll)B) {
        ll bb = b - B;
        int it = item_idx[bb];
        float v = 0.5f * bf2f(hi[(ll)it * 64 + d]) + 0.5f * bf2f(ui[(U + it) * 64 + d]);
        store_out(out, (ll)B * 64 + bb * 64 + d, v, bf);
    } else if (b < 3 * (ll)B) {
        ll bb = b - 2 * (ll)B;
        int it = item_idx[neg_idx[bb]];
        float v = 0.5f * bf2f(hi[(ll)it * 64 + d]) + 0.5f * bf2f(ui[(U + it) * 64 + d]);
        store_out(out, (ll)2 * B * 64 + bb * 64 + d, v, bf);
    }
}

extern "C" void kernel_launch(void* const* d_in, const int* in_sizes, int n_in,
                              void* d_out, int out_size, void* d_ws, size_t ws_size,
                              hipStream_t stream) {
    const int D = 64;
    const ll U = in_sizes[0] / D;
    const ll I = in_sizes[1] / D;
    const ll N = U + I;
    const ll E2  = in_sizes[8] / 2;
    const ll EU1 = in_sizes[9] / 2;
    const ll EU2 = in_sizes[10] / 2;
    const ll EI1 = in_sizes[11] / 2;
    const ll EI2 = in_sizes[12] / 2;
    const ll ET = E2 + EU1 + EU2 + EI1 + EI2;
    const ll RT = E2 + 2 * (EU1 + EU2 + EI1 + EI2);   // binning records
    const int B = in_sizes[13];
    const int M = (int)(N + 2 * U + 2 * I);           // CSR/in-deg index space
    const int M2 = (int)(N + 4 * U + 4 * I);          // + out-deg space
    const int K = (M2 + BIN_SIZE - 1) >> BIN_SHIFT;   // buckets
    const int KM = (M + BIN_SIZE - 1) >> BIN_SHIFT;   // buckets covering [0,M)
    if (K > KMAX) return;

    const void* user_feat = d_in[0];
    const void* item_feat = d_in[1];
    const int* uiR = (const int*)d_in[8];
    const int* uiC = uiR + E2;
    const int* u1s = (const int*)d_in[9];
    const int* u1d = u1s + EU1;
    const int* u2s = (const int*)d_in[10];
    const int* u2d = u2s + EU2;
    const int* i1s = (const int*)d_in[11];
    const int* i1d = i1s + EI1;
    const int* i2s = (const int*)d_in[12];
    const int* i2d = i2s + EI2;
    const int* user_idx = (const int*)d_in[13];
    const int* item_idx = (const int*)d_in[14];
    const int* neg_idx  = (const int*)d_in[15];

    const int T = 256;
    // ~252 WGs of 16 waves each; chunk rounded up to BT multiple.
    const ll CHUNKD = ((RT + 251) / 252 + (ll)BT - 1) / (ll)BT * (ll)BT;
    const int nWG_A = cdiv_ll(RT, CHUNKD);

    // ---------------- workspace layout ----------------
    ushort_t* q = (ushort_t*)d_ws;
    ushort_t* ui0 = q; q += N * 64;
    ushort_t* ui1 = q; q += N * 64;
    ushort_t* zi1 = q; q += I * 64;
    ushort_t* zi2 = q; q += I * 64;
    ushort_t* zu1 = q; q += U * 64;
    ushort_t* zu2 = q; q += U * 64;
    ushort_t* hu  = q; q += U * 64;
    ushort_t* hi  = q; q += I * 64;
    size_t feat_bytes = (size_t)(q - (ushort_t*)d_ws) * 2;
    if (feat_bytes < (size_t)RT * 4) return;   // binned overlay must fit (4B records)
    unsigned* binned = (unsigned*)d_ws;

    float* p = (float*)(((uintptr_t)q + 15) & ~(uintptr_t)15);
    float* nrm = p;  p += M2;
    ushort_t* Wbu = (ushort_t*)p; p += 64 * 128 / 2;
    ushort_t* Wbi = (ushort_t*)p; p += 64 * 128 / 2;
    float* wb1u = p; p += 128;
    float* ww2u = p; p += 128;
    float* wb1i = p; p += 128;
    float* ww2i = p; p += 128;
    float* scratch = p; p += 16;

    int* ip = (int*)p;
    int* btot = ip;    ip += KMAX * 32;
    int* bbase = ip;   ip += KMAX;
    int* bcursor = ip; ip += KMAX * 32;
    int* counts = ip;  ip += M2;
    int* S = ip;       ip += M + 1;
    ip = (int*)(((uintptr_t)ip + 7) & ~(uintptr_t)7);
    int2* ev_all = (int2*)ip; ip += 2 * ET;           // fused (col*64, norm) payload
    int* whist = ip;   ip += (size_t)nWG_A * K;       // per-WG bucket histograms
    int* bsum = ip;    ip += 256;
    int* flag = ip;    ip += 4;
    size_t needed = (size_t)((char*)ip - (char*)d_ws);
    if (ws_size < needed) return;

    // ---------------- dtype detection + weight conversion ----------------
    k_detect<<<1, 256, 0, stream>>>((const unsigned int*)user_feat, (ll)in_sizes[0] / 2, flag);
    k_cvt_weights<<<cdiv_ll(2 * (64 * 128 + 256), T), T, 0, stream>>>(
        d_in[2], d_in[3], d_in[4], d_in[5], d_in[6], d_in[7],
        Wbu, wb1u, ww2u, Wbi, wb1i, ww2i, flag);

    // ---------------- CSR build via 2-level binning ----------------
    hipMemsetAsync(btot, 0, (size_t)KMAX * 32 * sizeof(int), stream);
    hipMemsetAsync(scratch, 0, 16 * sizeof(float), stream);
    kA_hist<<<nWG_A, BT, 0, stream>>>(uiR, u1s, u1d, u2s, u2d, i1s, i1d, i2s, i2d,
                                      E2, EU1, EU2, EI1, EI2, (int)N, (int)U, (int)I, M,
                                      RT, CHUNKD, K, btot, whist);
    k_bscan<<<1, 1024, 0, stream>>>(btot, bbase, bcursor, K);
    kA_scatter<<<nWG_A, BT, 0, stream>>>(uiR, uiC, u1s, u1d, u2s, u2d, i1s, i1d, i2s, i2d,
                                         E2, EU1, EU2, EI1, EI2, (int)N, (int)U, (int)I, M,
                                         RT, CHUNKD, K, bcursor, whist, binned);
    kB1_count<<<K, T, 0, stream>>>(binned, bbase, btot, counts, M2);
    k_norm_all<<<cdiv_ll(M2, T), T, 0, stream>>>(counts, nrm, (int)N, M2);
    {
        int nb = (M + SCAN_CHUNK - 1) / SCAN_CHUNK;
        k_scanA<<<nb, SCAN_T, 0, stream>>>(counts, M, S, bsum);
        k_scanB<<<1, 256, 0, stream>>>(bsum, nb);
        k_scanC<<<cdiv_ll(M, T), T, 0, stream>>>(S, M, bsum, (int)ET);
    }
    kB2_fill<<<KM, T, 0, stream>>>(binned, bbase, btot, S, nrm,
                                   (int)N, (int)U, (int)I, M, ev_all);

    // ---------------- init features (after binned is consumed) ----------------
    k_init<<<cdiv_ll(N * 64, T), T, 0, stream>>>(user_feat, item_feat, ui0, hu, hi, U * 64, N * 64, flag);

    ushort_t* uiA = ui0;
    ushort_t* uiB = ui1;
    const int ATTN_HALF = 512;

    for (int layer = 0; layer < 2; layer++) {
        float* wsU = scratch + (layer ? 8 : 0);
        float* wsI = scratch + (layer ? 12 : 4);

        // ---- fused 5-way gather (ui, u1, u2, i1, i2) ----
        k_gather5<<<cdiv_ll((ll)M * 64, T), T, 0, stream>>>(
            S, ev_all, nrm, uiA, hu, hi,
            uiB, zu1, zu2, zi1, zi2,
            (int)N, (int)U, (int)I, M);
        { ushort_t* tmp = uiA; uiA = uiB; uiB = tmp; }

        // ---- fused attention scores (U half + I half) ----
        k_attn2<<<2 * ATTN_HALF, T, 0, stream>>>(
            zu1, zu2, Wbu, wb1u, ww2u, (int)U, wsU,
            zi1, zi2, Wbi, wb1i, ww2i, (int)I, wsI, ATTN_HALF);

        // ---- fused combine (hu + hi) ----
        k_combine2<<<cdiv_ll((U + I) * 64, T), T, 0, stream>>>(
            zu1, zu2, wsU, 1.0f / (float)U, hu, U * 64,
            zi1, zi2, wsI, 1.0f / (float)I, hi, (U + I) * 64);
    }

    // ---------------- final ----------------
    k_out<<<cdiv_ll((ll)3 * B * 64, T), T, 0, stream>>>(hu, hi, uiA, user_idx, item_idx, neg_idx,
                                                        d_out, B, U, flag);
}

// Round 10
// 737.836 us; speedup vs baseline: 1.1832x; 1.1358x over previous
//
#include <hip/hip_runtime.h>
#include <hip/hip_bf16.h>
#include <stdint.h>

typedef long long ll;
typedef unsigned short ushort_t;
typedef __attribute__((ext_vector_type(8))) short bf16x8;
typedef __attribute__((ext_vector_type(4))) float f32x4;

static inline int cdiv_ll(ll a, ll b) { return (int)((a + b - 1) / b); }

#define BIN_SHIFT 8
#define BIN_SIZE 256
#define KMAX 3072         // max buckets over M2 (M2 <= 786K)
#define BT 1024           // binning block threads (16 waves)
#define FILL_CAP 7936     // staged edges per bucket (63.5 KB LDS)

// ---------------- dtype detection (bf16 vs fp32 inputs) ----------------
__global__ void k_detect(const unsigned int* __restrict__ dw, const ll n_dw, int* __restrict__ flag) {
    __shared__ int sc[256];
    int tid = threadIdx.x;
    int cnt = 0;
    for (int s = 0; s < 32; s++) {
        ll idx = (ll)(s * 256 + tid);
        ll i = (idx * n_dw) / 8192;
        unsigned v = dw[i];
        unsigned lo = v & 0xFFFFu;
        unsigned ex = (lo >> 7) & 0xFFu;
        bool pl = (lo == 0u) || (lo == 0x8000u) || (ex >= 0x60u && ex <= 0x8Fu);
        cnt += pl ? 1 : 0;
    }
    sc[tid] = cnt;
    __syncthreads();
    for (int o = 128; o > 0; o >>= 1) { if (tid < o) sc[tid] += sc[tid + o]; __syncthreads(); }
    if (tid == 0) *flag = (sc[0] * 2 > 8192) ? 1 : 0;
}

__device__ __forceinline__ float load_in(const void* p, ll i, int isbf16) {
    if (isbf16) return __bfloat162float(((const __hip_bfloat16*)p)[i]);
    return ((const float*)p)[i];
}

__device__ __forceinline__ float bf2f(ushort_t u) {
    return __uint_as_float(((unsigned)u) << 16);
}
__device__ __forceinline__ ushort_t f2bf(float f) {
    unsigned u = __float_as_uint(f);
    unsigned r = (u + 0x7FFFu + ((u >> 16) & 1u)) >> 16;
    return (ushort_t)r;
}

// ---------------- fused weight conversion ----------------
__global__ void k_cvt_weights(const void* __restrict__ W1u, const void* __restrict__ b1u,
                              const void* __restrict__ w2u, const void* __restrict__ W1i,
                              const void* __restrict__ b1i, const void* __restrict__ w2i,
                              ushort_t* __restrict__ Wbu, float* __restrict__ fb1u,
                              float* __restrict__ fw2u, ushort_t* __restrict__ Wbi,
                              float* __restrict__ fb1i, float* __restrict__ fw2i,
                              const int* __restrict__ flag) {
    int i = blockIdx.x * blockDim.x + threadIdx.x;
    int bf = *flag;
    const int WSZ = 64 * 128;
    if (i < WSZ) {
        int d = i >> 7, h = i & 127;
        Wbu[h * 64 + d] = f2bf(load_in(W1u, i, bf));
    } else if (i < WSZ + 128) {
        fb1u[i - WSZ] = load_in(b1u, i - WSZ, bf);
    } else if (i < WSZ + 256) {
        fw2u[i - WSZ - 128] = load_in(w2u, i - WSZ - 128, bf);
    } else if (i < 2 * WSZ + 256) {
        int j = i - WSZ - 256;
        int d = j >> 7, h = j & 127;
        Wbi[h * 64 + d] = f2bf(load_in(W1i, j, bf));
    } else if (i < 2 * WSZ + 384) {
        fb1i[i - 2 * WSZ - 256] = load_in(b1i, i - 2 * WSZ - 256, bf);
    } else if (i < 2 * WSZ + 512) {
        fw2i[i - 2 * WSZ - 384] = load_in(w2i, i - 2 * WSZ - 384, bf);
    }
}

// ---------------- record decode (in-CSR + out-deg records, M2 keyspace) ----
__device__ __forceinline__ void decode_rec(ll t,
    const int* __restrict__ uiR, const int* __restrict__ uiC,
    const int* __restrict__ u1s, const int* __restrict__ u1d,
    const int* __restrict__ u2s, const int* __restrict__ u2d,
    const int* __restrict__ i1s, const int* __restrict__ i1d,
    const int* __restrict__ i2s, const int* __restrict__ i2d,
    const ll E2, const ll EU1, const ll EU2, const ll EI1, const ll EI2,
    const int N, const int U, const int I, const int M,
    int& key, int& col) {
    if (t < E2) { key = uiR[t]; col = uiC[t]; return; }
    t -= E2;
    if (t < EU1) { key = N + u1d[t]; col = u1s[t]; return; }
    t -= EU1;
    if (t < EU1) { key = M + u1s[t]; col = 0; return; }
    t -= EU1;
    if (t < EU2) { key = N + U + u2d[t]; col = u2s[t]; return; }
    t -= EU2;
    if (t < EU2) { key = M + U + u2s[t]; col = 0; return; }
    t -= EU2;
    if (t < EI1) { key = N + 2 * U + i1d[t]; col = i1s[t]; return; }
    t -= EI1;
    if (t < EI1) { key = M + 2 * U + i1s[t]; col = 0; return; }
    t -= EI1;
    if (t < EI2) { key = N + 2 * U + I + i2d[t]; col = i2s[t]; return; }
    t -= EI2;
    key = M + 2 * U + I + i2s[t]; col = 0;
}

// key-only decode (histogram pass never needs col)
__device__ __forceinline__ int decode_key(ll t,
    const int* __restrict__ uiR,
    const int* __restrict__ u1s, const int* __restrict__ u1d,
    const int* __restrict__ u2s, const int* __restrict__ u2d,
    const int* __restrict__ i1s, const int* __restrict__ i1d,
    const int* __restrict__ i2s, const int* __restrict__ i2d,
    const ll E2, const ll EU1, const ll EU2, const ll EI1, const ll EI2,
    const int N, const int U, const int I, const int M) {
    if (t < E2) return uiR[t];
    t -= E2;
    if (t < EU1) return N + u1d[t];
    t -= EU1;
    if (t < EU1) return M + u1s[t];
    t -= EU1;
    if (t < EU2) return N + U + u2d[t];
    t -= EU2;
    if (t < EU2) return M + U + u2s[t];
    t -= EU2;
    if (t < EI1) return N + 2 * U + i1d[t];
    t -= EI1;
    if (t < EI1) return M + 2 * U + i1s[t];
    t -= EI1;
    if (t < EI2) return N + 2 * U + I + i2d[t];
    t -= EI2;
    return M + 2 * U + I + i2s[t];
}

#define DECODE_ARGS uiR, uiC, u1s, u1d, u2s, u2d, i1s, i1d, i2s, i2d, \
                    E2, EU1, EU2, EI1, EI2, N, U, I, M

// ---------------- pass A1: per-WG LDS histogram ----------------
__global__ __launch_bounds__(BT) void kA_hist(
    const int* __restrict__ uiR,
    const int* __restrict__ u1s, const int* __restrict__ u1d,
    const int* __restrict__ u2s, const int* __restrict__ u2d,
    const int* __restrict__ i1s, const int* __restrict__ i1d,
    const int* __restrict__ i2s, const int* __restrict__ i2d,
    const ll E2, const ll EU1, const ll EU2, const ll EI1, const ll EI2,
    const int N, const int U, const int I, const int M,
    const ll RT, const ll CHUNKD, const int K,
    int* __restrict__ btot /* K*32 line-padded */,
    int* __restrict__ whist /* nWG x K */) {
    __shared__ int hist[KMAX];
    for (int i = threadIdx.x; i < K; i += BT) hist[i] = 0;
    __syncthreads();
    ll base = (ll)blockIdx.x * CHUNKD;
    ll lim = base + CHUNKD;
    if (lim > RT) lim = RT;
    for (ll t = base + threadIdx.x; t < lim; t += BT) {
        int key = decode_key(t, uiR, u1s, u1d, u2s, u2d, i1s, i1d, i2s, i2d,
                             E2, EU1, EU2, EI1, EI2, N, U, I, M);
        atomicAdd(&hist[key >> BIN_SHIFT], 1);
    }
    __syncthreads();
    ll wb = (ll)blockIdx.x * K;
    for (int k = threadIdx.x; k < K; k += BT) {
        int h = hist[k];
        whist[wb + k] = h;
        if (h) atomicAdd(&btot[k * 32], h);
    }
}

// ---------------- bucket scan: totals -> bases, init cursors ----------------
__global__ __launch_bounds__(1024) void k_bscan(const int* __restrict__ btot,
                                                int* __restrict__ bbase,
                                                int* __restrict__ bcursor, const int K) {
    __shared__ int sh[1024];
    __shared__ int carry;
    int t = threadIdx.x;
    if (t == 0) carry = 0;
    __syncthreads();
    for (int base = 0; base < K; base += 1024) {
        int idx = base + t;
        int v = (idx < K) ? btot[idx * 32] : 0;
        sh[t] = v;
        __syncthreads();
        for (int off = 1; off < 1024; off <<= 1) {
            int x = (t >= off) ? sh[t - off] : 0;
            __syncthreads();
            sh[t] += x;
            __syncthreads();
        }
        if (idx < K) {
            int ex = carry + sh[t] - v;
            bbase[idx] = ex;
            bcursor[idx * 32] = ex;
        }
        __syncthreads();
        if (t == 0) carry += sh[1023];
        __syncthreads();
    }
}

// ---------------- pass A2: scatter (single decode pass) -------
__global__ __launch_bounds__(BT) void kA_scatter(
    const int* __restrict__ uiR, const int* __restrict__ uiC,
    const int* __restrict__ u1s, const int* __restrict__ u1d,
    const int* __restrict__ u2s, const int* __restrict__ u2d,
    const int* __restrict__ i1s, const int* __restrict__ i1d,
    const int* __restrict__ i2s, const int* __restrict__ i2d,
    const ll E2, const ll EU1, const ll EU2, const ll EI1, const ll EI2,
    const int N, const int U, const int I, const int M,
    const ll RT, const ll CHUNKD, const int K, int* __restrict__ bcursor,
    const int* __restrict__ whist,
    unsigned* __restrict__ binned) {
    __shared__ int lcur[KMAX];
    ll wb = (ll)blockIdx.x * K;
    for (int k = threadIdx.x; k < K; k += BT) {
        int h = whist[wb + k];
        lcur[k] = h ? atomicAdd(&bcursor[k * 32], h) : 0;
    }
    __syncthreads();
    ll base = (ll)blockIdx.x * CHUNKD;
    ll lim = base + CHUNKD;
    if (lim > RT) lim = RT;
    for (ll t = base + threadIdx.x; t < lim; t += BT) {
        int key, col;
        decode_rec(t, DECODE_ARGS, key, col);
        int pos = atomicAdd(&lcur[key >> BIN_SHIFT], 1);
        binned[pos] = ((unsigned)(key & 255) << 24) | (unsigned)col;
    }
}

// ---------------- pass B1: per-bucket LDS count -> counts array ----------
__global__ __launch_bounds__(256) void kB1_count(const unsigned* __restrict__ binned,
                                                 const int* __restrict__ bbase,
                                                 const int* __restrict__ btot,
                                                 int* __restrict__ counts, const int M2) {
    __shared__ int cnt[BIN_SIZE];
    int b = blockIdx.x;
    int lo = b << BIN_SHIFT;
    int hi = min(lo + BIN_SIZE, M2);
    for (int i = threadIdx.x; i < BIN_SIZE; i += 256) cnt[i] = 0;
    __syncthreads();
    int s = bbase[b], n = btot[b * 32];
    for (int j = s + threadIdx.x; j < s + n; j += 256) {
        atomicAdd(&cnt[binned[j] >> 24], 1);
    }
    __syncthreads();
    for (int i = threadIdx.x; i < hi - lo; i += 256) counts[lo + i] = cnt[i];
}

// ---------------- fused norms ----------------
__global__ void k_norm_all(const int* __restrict__ counts, float* __restrict__ nrm,
                           const int N, const int total) {
    int i = blockIdx.x * blockDim.x + threadIdx.x;
    if (i < total) {
        int c = counts[i];
        if (i < N) nrm[i] = (c > 0) ? (1.0f / sqrtf((float)c)) : 0.0f;
        else nrm[i] = 1.0f / sqrtf(fmaxf((float)c, 1.0f));
    }
}

// ---------------- hierarchical exclusive scan ----------
#define SCAN_T 256
#define SCAN_ELEMS 8
#define SCAN_CHUNK (SCAN_T * SCAN_ELEMS)   // 2048

__global__ __launch_bounds__(256) void k_scanA(const int* __restrict__ in, const int n,
                                               int* __restrict__ out, int* __restrict__ bsum) {
    __shared__ int sh[SCAN_T];
    int t = threadIdx.x;
    ll base = (ll)blockIdx.x * SCAN_CHUNK + (ll)t * SCAN_ELEMS;
    int v[SCAN_ELEMS];
    int tot = 0;
#pragma unroll
    for (int k = 0; k < SCAN_ELEMS; k++) {
        ll i = base + k;
        v[k] = (i < n) ? in[i] : 0;
        tot += v[k];
    }
    sh[t] = tot;
    __syncthreads();
    for (int off = 1; off < SCAN_T; off <<= 1) {
        int x = (t >= off) ? sh[t - off] : 0;
        __syncthreads();
        sh[t] += x;
        __syncthreads();
    }
    int run = sh[t] - tot;
#pragma unroll
    for (int k = 0; k < SCAN_ELEMS; k++) {
        ll i = base + k;
        if (i < n) out[i] = run;
        run += v[k];
    }
    if (t == SCAN_T - 1) bsum[blockIdx.x] = sh[SCAN_T - 1];
}

__global__ __launch_bounds__(256) void k_scanB(int* __restrict__ bsum, const int nb) {
    __shared__ int sh[256];
    int t = threadIdx.x;
    int running = 0;
    for (int base = 0; base < nb; base += 256) {
        int idx = base + t;
        int v = (idx < nb) ? bsum[idx] : 0;
        sh[t] = v;
        __syncthreads();
        for (int off = 1; off < 256; off <<= 1) {
            int x = (t >= off) ? sh[t - off] : 0;
            __syncthreads();
            sh[t] += x;
            __syncthreads();
        }
        if (idx < nb) bsum[idx] = running + sh[t] - v;
        int tot = sh[255];
        __syncthreads();
        running += tot;
    }
}

__global__ void k_scanC(int* __restrict__ S, const int n, const int* __restrict__ bsum, const int ET) {
    ll i = (ll)blockIdx.x * blockDim.x + threadIdx.x;
    if (i < n) S[i] += bsum[i / SCAN_CHUNK];
    if (i == 0) S[n] = ET;
}

// ---------------- pass B2: per-bucket CSR fill, LDS-staged ----------
__global__ __launch_bounds__(256) void kB2_fill(const unsigned* __restrict__ binned,
                                                const int* __restrict__ bbase,
                                                const int* __restrict__ btot,
                                                const int* __restrict__ S,
                                                const float* __restrict__ nrm,
                                                const int N, const int U, const int I,
                                                const int M,
                                                int2* __restrict__ ev_all) {
    __shared__ int scur[BIN_SIZE];
    __shared__ int2 buf[FILL_CAP];
    int b = blockIdx.x;
    int lo = b << BIN_SHIFT;
    int hi = min(lo + BIN_SIZE, M);
    int obase = S[lo];
    int nfill = S[hi] - obase;
    int s = bbase[b], n = btot[b * 32];
    const int segU = N + U, seg2U = N + 2 * U, segI = N + 2 * U + I;
    if (n <= FILL_CAP) {
        for (int i = threadIdx.x; i < hi - lo; i += 256) scur[i] = S[lo + i] - obase;
        __syncthreads();
        for (int j = s + threadIdx.x; j < s + n; j += 256) {
            unsigned rec = binned[j];
            int key = lo + (int)(rec >> 24);
            if (key < M) {
                int pos = atomicAdd(&scur[key - lo], 1);
                int col = (int)(rec & 0xFFFFFFu);
                int nidx;
                if (key < N)          nidx = col;                   // ui: dinv[col]
                else if (key < segU)  nidx = M + col;               // u1 src out-deg norm
                else if (key < seg2U) nidx = M + U + col;           // u2
                else if (key < segI)  nidx = M + 2 * U + col;       // i1
                else                  nidx = M + 2 * U + I + col;   // i2
                buf[pos] = make_int2(col * 64, __float_as_int(nrm[nidx]));
            }
        }
        __syncthreads();
        for (int i = threadIdx.x; i < nfill; i += 256)
            ev_all[obase + i] = buf[i];
    } else {
        // fallback: direct scatter (correct for any bucket size)
        for (int i = threadIdx.x; i < hi - lo; i += 256) scur[i] = S[lo + i];
        __syncthreads();
        for (int j = s + threadIdx.x; j < s + n; j += 256) {
            unsigned rec = binned[j];
            int key = lo + (int)(rec >> 24);
            if (key < M) {
                int pos = atomicAdd(&scur[key - lo], 1);
                int col = (int)(rec & 0xFFFFFFu);
                int nidx;
                if (key < N)          nidx = col;
                else if (key < segU)  nidx = M + col;
                else if (key < seg2U) nidx = M + U + col;
                else if (key < segI)  nidx = M + 2 * U + col;
                else                  nidx = M + 2 * U + I + col;
                ev_all[pos] = make_int2(col * 64, __float_as_int(nrm[nidx]));
            }
        }
    }
}

// ---------------- init features (bf16 storage) ----------------
__global__ void k_init(const void* __restrict__ uf, const void* __restrict__ itf,
                       ushort_t* __restrict__ ui, ushort_t* __restrict__ hu,
                       ushort_t* __restrict__ hi,
                       const ll nu64, const ll ntot64, const int* __restrict__ flag) {
    ll t = (ll)blockIdx.x * blockDim.x + threadIdx.x;
    int bf = *flag;
    if (t < nu64) {
        ushort_t v = bf ? ((const ushort_t*)uf)[t] : f2bf(((const float*)uf)[t]);
        ui[t] = v; hu[t] = v;
    } else if (t < ntot64) {
        ll j = t - nu64;
        ushort_t v = bf ? ((const ushort_t*)itf)[j] : f2bf(((const float*)itf)[j]);
        ui[t] = v; hi[j] = v;
    }
}

// ---------------- fused 5-segment gather SpMM, 16 lanes/row ----------------
// R9 showed row-per-wave = 24 cyc/edge latency chain (HBM 22%, VALU 32%).
// 16 lanes/row (short4 per lane) puts 4 independent rows in flight per wave:
// same 128B coalesced line per edge, 4x the edge-chains per wave.
typedef __attribute__((ext_vector_type(4))) unsigned short ushort4v;

__global__ __launch_bounds__(256) void k_gather5(const int* __restrict__ S,
                                                 const int2* __restrict__ ev,
                                                 const float* __restrict__ nrm,
                                                 const ushort_t* __restrict__ xui,
                                                 const ushort_t* __restrict__ xu,
                                                 const ushort_t* __restrict__ xi,
                                                 ushort_t* __restrict__ out_ui,
                                                 ushort_t* __restrict__ o_zu1,
                                                 ushort_t* __restrict__ o_zu2,
                                                 ushort_t* __restrict__ o_zi1,
                                                 ushort_t* __restrict__ o_zi2,
                                                 const int N, const int U, const int I,
                                                 const int M) {
    ll gt = (ll)blockIdx.x * blockDim.x + threadIdx.x;
    int w = (int)(gt >> 4);             // 16 threads per row
    int l16 = threadIdx.x & 15;         // covers dims [l16*4, l16*4+4)
    if (w >= M) return;
    const ushort_t* x;
    ushort_t* out;
    int orow;
    if (w < N)                  { x = xui; out = out_ui; orow = w; }
    else if (w < N + U)         { x = xu;  out = o_zu1;  orow = w - N; }
    else if (w < N + 2 * U)     { x = xu;  out = o_zu2;  orow = w - N - U; }
    else if (w < N + 2 * U + I) { x = xi;  out = o_zi1;  orow = w - N - 2 * U; }
    else                        { x = xi;  out = o_zi2;  orow = w - N - 2 * U - I; }
    int s = S[w], e = S[w + 1];
    float a0 = 0.0f, a1 = 0.0f, a2 = 0.0f, a3 = 0.0f;
    unsigned doff = (unsigned)(l16 * 4);
    for (int j = s; j < e; j += 8) {
#pragma unroll
        for (int k = 0; k < 8; k++) {
            int jj = j + k;
            bool live = jj < e;
            int2 pr = ev[live ? jj : s];
            float nn = live ? __int_as_float(pr.y) : 0.0f;
            unsigned off = (unsigned)pr.x + doff;
            ushort4v xv = *(const ushort4v*)&x[off];
            a0 += bf2f(xv.x) * nn;
            a1 += bf2f(xv.y) * nn;
            a2 += bf2f(xv.z) * nn;
            a3 += bf2f(xv.w) * nn;
        }
    }
    float rn = nrm[w];
    ushort4v o;
    o.x = f2bf(a0 * rn); o.y = f2bf(a1 * rn);
    o.z = f2bf(a2 * rn); o.w = f2bf(a3 * rn);
    *(ushort4v*)&out[(ll)orow * 64 + doff] = o;
}

// ---------------- fast tanh ----------
__device__ __forceinline__ float fast_tanh(float x) {
    return 1.0f - 2.0f / (__expf(2.0f * x) + 1.0f);
}

// ---------------- MFMA semantic-attention scores, fused U+I halves --------
__global__ __launch_bounds__(256) void k_attn2(const ushort_t* __restrict__ zu1,
                                               const ushort_t* __restrict__ zu2,
                                               const ushort_t* __restrict__ Wbu,
                                               const float* __restrict__ b1u,
                                               const float* __restrict__ w2u,
                                               const int nU, float* __restrict__ wsU,
                                               const ushort_t* __restrict__ zi1,
                                               const ushort_t* __restrict__ zi2,
                                               const ushort_t* __restrict__ Wbi,
                                               const float* __restrict__ b1f_i,
                                               const float* __restrict__ w2f_i,
                                               const int nI, float* __restrict__ wsI,
                                               const int half) {
    __shared__ float red0[4], red1[4];
    bool isU = (int)blockIdx.x < half;
    const ushort_t* z1 = isU ? zu1 : zi1;
    const ushort_t* z2 = isU ? zu2 : zi2;
    const ushort_t* Wb = isU ? Wbu : Wbi;
    const float* b1f = isU ? b1u : b1f_i;
    const float* w2f = isU ? w2u : w2f_i;
    const int n = isU ? nU : nI;
    float* wsum = isU ? wsU : wsI;
    int blk = isU ? (int)blockIdx.x : (int)blockIdx.x - half;

    int tid = threadIdx.x;
    int lane = tid & 63;
    int wid = tid >> 6;
    int col = lane & 15;
    int quad = lane >> 4;

    bf16x8 wb[8][2];
#pragma unroll
    for (int ht = 0; ht < 8; ht++) {
        int h = ht * 16 + col;
#pragma unroll
        for (int ks = 0; ks < 2; ks++) {
            wb[ht][ks] = *(const bf16x8*)&Wb[h * 64 + ks * 32 + quad * 8];
        }
    }
    float b1v[8], w2v[8];
#pragma unroll
    for (int ht = 0; ht < 8; ht++) {
        b1v[ht] = b1f[ht * 16 + col];
        w2v[ht] = w2f[ht * 16 + col];
    }

    float w0 = 0.0f, w1 = 0.0f;
    int ntiles = (n + 15) >> 4;
    int gw = blk * 4 + wid;
    int nw = half * 4;
    const bf16x8 zero8 = {0, 0, 0, 0, 0, 0, 0, 0};

    for (int tile = gw; tile < ntiles; tile += nw) {
        int nodeA = tile * 16 + col;
        bool va = nodeA < n;
        bf16x8 a1[2], a2[2];
#pragma unroll
        for (int ks = 0; ks < 2; ks++) {
            const bf16x8* p1 = (const bf16x8*)&z1[(ll)nodeA * 64 + ks * 32 + quad * 8];
            const bf16x8* p2 = (const bf16x8*)&z2[(ll)nodeA * 64 + ks * 32 + quad * 8];
            a1[ks] = va ? p1[0] : zero8;
            a2[ks] = va ? p2[0] : zero8;
        }
#pragma unroll
        for (int ht = 0; ht < 8; ht++) {
            f32x4 c1 = {0.f, 0.f, 0.f, 0.f};
            f32x4 c2 = {0.f, 0.f, 0.f, 0.f};
            c1 = __builtin_amdgcn_mfma_f32_16x16x32_bf16(a1[0], wb[ht][0], c1, 0, 0, 0);
            c1 = __builtin_amdgcn_mfma_f32_16x16x32_bf16(a1[1], wb[ht][1], c1, 0, 0, 0);
            c2 = __builtin_amdgcn_mfma_f32_16x16x32_bf16(a2[0], wb[ht][0], c2, 0, 0, 0);
            c2 = __builtin_amdgcn_mfma_f32_16x16x32_bf16(a2[1], wb[ht][1], c2, 0, 0, 0);
#pragma unroll
            for (int r = 0; r < 4; r++) {
                int node_row = tile * 16 + quad * 4 + r;
                bool vr = node_row < n;
                float t1 = fast_tanh(c1[r] + b1v[ht]) * w2v[ht];
                float t2 = fast_tanh(c2[r] + b1v[ht]) * w2v[ht];
                w0 += vr ? t1 : 0.0f;
                w1 += vr ? t2 : 0.0f;
            }
        }
    }

    for (int off = 32; off > 0; off >>= 1) {
        w0 += __shfl_down(w0, off);
        w1 += __shfl_down(w1, off);
    }
    if (lane == 0) { red0[wid] = w0; red1[wid] = w1; }
    __syncthreads();
    if (tid == 0) {
        atomicAdd(&wsum[0], red0[0] + red0[1] + red0[2] + red0[3]);
        atomicAdd(&wsum[1], red1[0] + red1[1] + red1[2] + red1[3]);
    }
}

// ---------------- fused combine (U then I), inline beta softmax ----------
__global__ void k_combine2(const ushort_t* __restrict__ zu1, const ushort_t* __restrict__ zu2,
                           const float* __restrict__ wsU, const float inv_nU,
                           ushort_t* __restrict__ hu, const ll nu64,
                           const ushort_t* __restrict__ zi1, const ushort_t* __restrict__ zi2,
                           const float* __restrict__ wsI, const float inv_nI,
                           ushort_t* __restrict__ hi, const ll ntot64) {
    ll t = (ll)blockIdx.x * blockDim.x + threadIdx.x;
    if (t < nu64) {
        float m0 = wsU[0] * inv_nU, m1 = wsU[1] * inv_nU;
        float mx = fmaxf(m0, m1);
        float e0 = __expf(m0 - mx), e1 = __expf(m1 - mx);
        float inv_s = 1.0f / (e0 + e1);
        hu[t] = f2bf((e0 * bf2f(zu1[t]) + e1 * bf2f(zu2[t])) * inv_s);
    } else if (t < ntot64) {
        ll j = t - nu64;
        float m0 = wsI[0] * inv_nI, m1 = wsI[1] * inv_nI;
        float mx = fmaxf(m0, m1);
        float e0 = __expf(m0 - mx), e1 = __expf(m1 - mx);
        float inv_s = 1.0f / (e0 + e1);
        hi[j] = f2bf((e0 * bf2f(zi1[j]) + e1 * bf2f(zi2[j])) * inv_s);
    }
}

// ---------------- fused output gather ----------------
__device__ __forceinline__ void store_out(void* out, ll i, float v, int isbf16) {
    if (isbf16) ((ushort_t*)out)[i] = f2bf(v);
    else ((float*)out)[i] = v;
}

__global__ void k_out(const ushort_t* __restrict__ hu, const ushort_t* __restrict__ hi,
                      const ushort_t* __restrict__ ui, const int* __restrict__ user_idx,
                      const int* __restrict__ item_idx, const int* __restrict__ neg_idx,
                      void* __restrict__ out, const int B, const ll U,
                      const int* __restrict__ flag) {
    ll t = (ll)blockIdx.x * blockDim.x + threadIdx.x;
    int bf = *flag;
    int d = (int)(t & 63);
    ll b = t >> 6;
    if (b < B) {
        int u = user_idx[b];
        float v = 0.5f * bf2f(hu[(ll)u * 64 + d]) + 0.5f * bf2f(ui[(ll)u * 64 + d]);
        store_out(out, b * 64 + d, v, bf);
    } else if (b < 2 * (ll)B) {
        ll bb = b - B;
        int it = item_idx[bb];
        float v = 0.5f * bf2f(hi[(ll)it * 64 + d]) + 0.5f * bf2f(ui[(U + it) * 64 + d]);
        store_out(out, (ll)B * 64 + bb * 64 + d, v, bf);
    } else if (b < 3 * (ll)B) {
        ll bb = b - 2 * (ll)B;
        int it = item_idx[neg_idx[bb]];
        float v = 0.5f * bf2f(hi[(ll)it * 64 + d]) + 0.5f * bf2f(ui[(U + it) * 64 + d]);
        store_out(out, (ll)2 * B * 64 + bb * 64 + d, v, bf);
    }
}

extern "C" void kernel_launch(void* const* d_in, const int* in_sizes, int n_in,
                              void* d_out, int out_size, void* d_ws, size_t ws_size,
                              hipStream_t stream) {
    const int D = 64;
    const ll U = in_sizes[0] / D;
    const ll I = in_sizes[1] / D;
    const ll N = U + I;
    const ll E2  = in_sizes[8] / 2;
    const ll EU1 = in_sizes[9] / 2;
    const ll EU2 = in_sizes[10] / 2;
    const ll EI1 = in_sizes[11] / 2;
    const ll EI2 = in_sizes[12] / 2;
    const ll ET = E2 + EU1 + EU2 + EI1 + EI2;
    const ll RT = E2 + 2 * (EU1 + EU2 + EI1 + EI2);   // binning records
    const int B = in_sizes[13];
    const int M = (int)(N + 2 * U + 2 * I);           // CSR/in-deg index space
    const int M2 = (int)(N + 4 * U + 4 * I);          // + out-deg space
    const int K = (M2 + BIN_SIZE - 1) >> BIN_SHIFT;   // buckets
    const int KM = (M + BIN_SIZE - 1) >> BIN_SHIFT;   // buckets covering [0,M)
    if (K > KMAX) return;

    const void* user_feat = d_in[0];
    const void* item_feat = d_in[1];
    const int* uiR = (const int*)d_in[8];
    const int* uiC = uiR + E2;
    const int* u1s = (const int*)d_in[9];
    const int* u1d = u1s + EU1;
    const int* u2s = (const int*)d_in[10];
    const int* u2d = u2s + EU2;
    const int* i1s = (const int*)d_in[11];
    const int* i1d = i1s + EI1;
    const int* i2s = (const int*)d_in[12];
    const int* i2d = i2s + EI2;
    const int* user_idx = (const int*)d_in[13];
    const int* item_idx = (const int*)d_in[14];
    const int* neg_idx  = (const int*)d_in[15];

    const int T = 256;
    // ~252 WGs of 16 waves each; chunk rounded up to BT multiple.
    const ll CHUNKD = ((RT + 251) / 252 + (ll)BT - 1) / (ll)BT * (ll)BT;
    const int nWG_A = cdiv_ll(RT, CHUNKD);

    // ---------------- workspace layout ----------------
    ushort_t* q = (ushort_t*)d_ws;
    ushort_t* ui0 = q; q += N * 64;
    ushort_t* ui1 = q; q += N * 64;
    ushort_t* zi1 = q; q += I * 64;
    ushort_t* zi2 = q; q += I * 64;
    ushort_t* zu1 = q; q += U * 64;
    ushort_t* zu2 = q; q += U * 64;
    ushort_t* hu  = q; q += U * 64;
    ushort_t* hi  = q; q += I * 64;
    size_t feat_bytes = (size_t)(q - (ushort_t*)d_ws) * 2;
    if (feat_bytes < (size_t)RT * 4) return;   // binned overlay must fit (4B records)
    unsigned* binned = (unsigned*)d_ws;

    float* p = (float*)(((uintptr_t)q + 15) & ~(uintptr_t)15);
    float* nrm = p;  p += M2;
    ushort_t* Wbu = (ushort_t*)p; p += 64 * 128 / 2;
    ushort_t* Wbi = (ushort_t*)p; p += 64 * 128 / 2;
    float* wb1u = p; p += 128;
    float* ww2u = p; p += 128;
    float* wb1i = p; p += 128;
    float* ww2i = p; p += 128;
    float* scratch = p; p += 16;

    int* ip = (int*)p;
    int* btot = ip;    ip += KMAX * 32;
    int* bbase = ip;   ip += KMAX;
    int* bcursor = ip; ip += KMAX * 32;
    int* counts = ip;  ip += M2;
    int* S = ip;       ip += M + 1;
    ip = (int*)(((uintptr_t)ip + 7) & ~(uintptr_t)7);
    int2* ev_all = (int2*)ip; ip += 2 * ET;           // fused (col*64, norm) payload
    int* whist = ip;   ip += (size_t)nWG_A * K;       // per-WG bucket histograms
    int* bsum = ip;    ip += 256;
    int* flag = ip;    ip += 4;
    size_t needed = (size_t)((char*)ip - (char*)d_ws);
    if (ws_size < needed) return;

    // ---------------- dtype detection + weight conversion ----------------
    k_detect<<<1, 256, 0, stream>>>((const unsigned int*)user_feat, (ll)in_sizes[0] / 2, flag);
    k_cvt_weights<<<cdiv_ll(2 * (64 * 128 + 256), T), T, 0, stream>>>(
        d_in[2], d_in[3], d_in[4], d_in[5], d_in[6], d_in[7],
        Wbu, wb1u, ww2u, Wbi, wb1i, ww2i, flag);

    // ---------------- CSR build via 2-level binning ----------------
    hipMemsetAsync(btot, 0, (size_t)KMAX * 32 * sizeof(int), stream);
    hipMemsetAsync(scratch, 0, 16 * sizeof(float), stream);
    kA_hist<<<nWG_A, BT, 0, stream>>>(uiR, u1s, u1d, u2s, u2d, i1s, i1d, i2s, i2d,
                                      E2, EU1, EU2, EI1, EI2, (int)N, (int)U, (int)I, M,
                                      RT, CHUNKD, K, btot, whist);
    k_bscan<<<1, 1024, 0, stream>>>(btot, bbase, bcursor, K);
    kA_scatter<<<nWG_A, BT, 0, stream>>>(uiR, uiC, u1s, u1d, u2s, u2d, i1s, i1d, i2s, i2d,
                                         E2, EU1, EU2, EI1, EI2, (int)N, (int)U, (int)I, M,
                                         RT, CHUNKD, K, bcursor, whist, binned);
    kB1_count<<<K, T, 0, stream>>>(binned, bbase, btot, counts, M2);
    k_norm_all<<<cdiv_ll(M2, T), T, 0, stream>>>(counts, nrm, (int)N, M2);
    {
        int nb = (M + SCAN_CHUNK - 1) / SCAN_CHUNK;
        k_scanA<<<nb, SCAN_T, 0, stream>>>(counts, M, S, bsum);
        k_scanB<<<1, 256, 0, stream>>>(bsum, nb);
        k_scanC<<<cdiv_ll(M, T), T, 0, stream>>>(S, M, bsum, (int)ET);
    }
    kB2_fill<<<KM, T, 0, stream>>>(binned, bbase, btot, S, nrm,
                                   (int)N, (int)U, (int)I, M, ev_all);

    // ---------------- init features (after binned is consumed) ----------------
    k_init<<<cdiv_ll(N * 64, T), T, 0, stream>>>(user_feat, item_feat, ui0, hu, hi, U * 64, N * 64, flag);

    ushort_t* uiA = ui0;
    ushort_t* uiB = ui1;
    const int ATTN_HALF = 512;

    for (int layer = 0; layer < 2; layer++) {
        float* wsU = scratch + (layer ? 8 : 0);
        float* wsI = scratch + (layer ? 12 : 4);

        // ---- fused 5-way gather (ui, u1, u2, i1, i2), 16 lanes/row ----
        k_gather5<<<cdiv_ll((ll)M * 16, T), T, 0, stream>>>(
            S, ev_all, nrm, uiA, hu, hi,
            uiB, zu1, zu2, zi1, zi2,
            (int)N, (int)U, (int)I, M);
        { ushort_t* tmp = uiA; uiA = uiB; uiB = tmp; }

        // ---- fused attention scores (U half + I half) ----
        k_attn2<<<2 * ATTN_HALF, T, 0, stream>>>(
            zu1, zu2, Wbu, wb1u, ww2u, (int)U, wsU,
            zi1, zi2, Wbi, wb1i, ww2i, (int)I, wsI, ATTN_HALF);

        // ---- fused combine (hu + hi) ----
        k_combine2<<<cdiv_ll((U + I) * 64, T), T, 0, stream>>>(
            zu1, zu2, wsU, 1.0f / (float)U, hu, U * 64,
            zi1, zi2, wsI, 1.0f / (float)I, hi, (U + I) * 64);
    }

    // ---------------- final ----------------
    k_out<<<cdiv_ll((ll)3 * B * 64, T), T, 0, stream>>>(hu, hi, uiA, user_idx, item_idx, neg_idx,
                                                        d_out, B, U, flag);
}

// Round 11
// 651.817 us; speedup vs baseline: 1.3394x; 1.1320x over previous
//
#include <hip/hip_runtime.h>
#include <hip/hip_bf16.h>
#include <stdint.h>

typedef long long ll;
typedef unsigned short ushort_t;
typedef __attribute__((ext_vector_type(8))) short bf16x8;
typedef __attribute__((ext_vector_type(4))) float f32x4;

static inline int cdiv_ll(ll a, ll b) { return (int)((a + b - 1) / b); }

#define BIN_SHIFT 8
#define BIN_SIZE 256
#define KMAX 3072         // max buckets over M2 (M2 <= 786K)
#define BT 1024           // binning block threads (16 waves)
#define FILL_CAP 7936     // staged edges per bucket (63.5 KB LDS)

// ---------------- dtype detection (bf16 vs fp32 inputs) ----------------
__global__ void k_detect(const unsigned int* __restrict__ dw, const ll n_dw, int* __restrict__ flag) {
    __shared__ int sc[256];
    int tid = threadIdx.x;
    int cnt = 0;
    for (int s = 0; s < 32; s++) {
        ll idx = (ll)(s * 256 + tid);
        ll i = (idx * n_dw) / 8192;
        unsigned v = dw[i];
        unsigned lo = v & 0xFFFFu;
        unsigned ex = (lo >> 7) & 0xFFu;
        bool pl = (lo == 0u) || (lo == 0x8000u) || (ex >= 0x60u && ex <= 0x8Fu);
        cnt += pl ? 1 : 0;
    }
    sc[tid] = cnt;
    __syncthreads();
    for (int o = 128; o > 0; o >>= 1) { if (tid < o) sc[tid] += sc[tid + o]; __syncthreads(); }
    if (tid == 0) *flag = (sc[0] * 2 > 8192) ? 1 : 0;
}

__device__ __forceinline__ float load_in(const void* p, ll i, int isbf16) {
    if (isbf16) return __bfloat162float(((const __hip_bfloat16*)p)[i]);
    return ((const float*)p)[i];
}

__device__ __forceinline__ float bf2f(ushort_t u) {
    return __uint_as_float(((unsigned)u) << 16);
}
__device__ __forceinline__ ushort_t f2bf(float f) {
    unsigned u = __float_as_uint(f);
    unsigned r = (u + 0x7FFFu + ((u >> 16) & 1u)) >> 16;
    return (ushort_t)r;
}

// ---------------- fused weight conversion ----------------
__global__ void k_cvt_weights(const void* __restrict__ W1u, const void* __restrict__ b1u,
                              const void* __restrict__ w2u, const void* __restrict__ W1i,
                              const void* __restrict__ b1i, const void* __restrict__ w2i,
                              ushort_t* __restrict__ Wbu, float* __restrict__ fb1u,
                              float* __restrict__ fw2u, ushort_t* __restrict__ Wbi,
                              float* __restrict__ fb1i, float* __restrict__ fw2i,
                              const int* __restrict__ flag) {
    int i = blockIdx.x * blockDim.x + threadIdx.x;
    int bf = *flag;
    const int WSZ = 64 * 128;
    if (i < WSZ) {
        int d = i >> 7, h = i & 127;
        Wbu[h * 64 + d] = f2bf(load_in(W1u, i, bf));
    } else if (i < WSZ + 128) {
        fb1u[i - WSZ] = load_in(b1u, i - WSZ, bf);
    } else if (i < WSZ + 256) {
        fw2u[i - WSZ - 128] = load_in(w2u, i - WSZ - 128, bf);
    } else if (i < 2 * WSZ + 256) {
        int j = i - WSZ - 256;
        int d = j >> 7, h = j & 127;
        Wbi[h * 64 + d] = f2bf(load_in(W1i, j, bf));
    } else if (i < 2 * WSZ + 384) {
        fb1i[i - 2 * WSZ - 256] = load_in(b1i, i - 2 * WSZ - 256, bf);
    } else if (i < 2 * WSZ + 512) {
        fw2i[i - 2 * WSZ - 384] = load_in(w2i, i - 2 * WSZ - 384, bf);
    }
}

// ---------------- record decode (in-CSR + out-deg records, M2 keyspace) ----
__device__ __forceinline__ void decode_rec(ll t,
    const int* __restrict__ uiR, const int* __restrict__ uiC,
    const int* __restrict__ u1s, const int* __restrict__ u1d,
    const int* __restrict__ u2s, const int* __restrict__ u2d,
    const int* __restrict__ i1s, const int* __restrict__ i1d,
    const int* __restrict__ i2s, const int* __restrict__ i2d,
    const ll E2, const ll EU1, const ll EU2, const ll EI1, const ll EI2,
    const int N, const int U, const int I, const int M,
    int& key, int& col) {
    if (t < E2) { key = uiR[t]; col = uiC[t]; return; }
    t -= E2;
    if (t < EU1) { key = N + u1d[t]; col = u1s[t]; return; }
    t -= EU1;
    if (t < EU1) { key = M + u1s[t]; col = 0; return; }
    t -= EU1;
    if (t < EU2) { key = N + U + u2d[t]; col = u2s[t]; return; }
    t -= EU2;
    if (t < EU2) { key = M + U + u2s[t]; col = 0; return; }
    t -= EU2;
    if (t < EI1) { key = N + 2 * U + i1d[t]; col = i1s[t]; return; }
    t -= EI1;
    if (t < EI1) { key = M + 2 * U + i1s[t]; col = 0; return; }
    t -= EI1;
    if (t < EI2) { key = N + 2 * U + I + i2d[t]; col = i2s[t]; return; }
    t -= EI2;
    key = M + 2 * U + I + i2s[t]; col = 0;
}

// key-only decode (histogram pass never needs col)
__device__ __forceinline__ int decode_key(ll t,
    const int* __restrict__ uiR,
    const int* __restrict__ u1s, const int* __restrict__ u1d,
    const int* __restrict__ u2s, const int* __restrict__ u2d,
    const int* __restrict__ i1s, const int* __restrict__ i1d,
    const int* __restrict__ i2s, const int* __restrict__ i2d,
    const ll E2, const ll EU1, const ll EU2, const ll EI1, const ll EI2,
    const int N, const int U, const int I, const int M) {
    if (t < E2) return uiR[t];
    t -= E2;
    if (t < EU1) return N + u1d[t];
    t -= EU1;
    if (t < EU1) return M + u1s[t];
    t -= EU1;
    if (t < EU2) return N + U + u2d[t];
    t -= EU2;
    if (t < EU2) return M + U + u2s[t];
    t -= EU2;
    if (t < EI1) return N + 2 * U + i1d[t];
    t -= EI1;
    if (t < EI1) return M + 2 * U + i1s[t];
    t -= EI1;
    if (t < EI2) return N + 2 * U + I + i2d[t];
    t -= EI2;
    return M + 2 * U + I + i2s[t];
}

#define DECODE_ARGS uiR, uiC, u1s, u1d, u2s, u2d, i1s, i1d, i2s, i2d, \
                    E2, EU1, EU2, EI1, EI2, N, U, I, M

// ---------------- pass A1: per-WG LDS histogram ----------------
__global__ __launch_bounds__(BT) void kA_hist(
    const int* __restrict__ uiR,
    const int* __restrict__ u1s, const int* __restrict__ u1d,
    const int* __restrict__ u2s, const int* __restrict__ u2d,
    const int* __restrict__ i1s, const int* __restrict__ i1d,
    const int* __restrict__ i2s, const int* __restrict__ i2d,
    const ll E2, const ll EU1, const ll EU2, const ll EI1, const ll EI2,
    const int N, const int U, const int I, const int M,
    const ll RT, const ll CHUNKD, const int K,
    int* __restrict__ btot /* K*32 line-padded */,
    int* __restrict__ whist /* nWG x K */) {
    __shared__ int hist[KMAX];
    for (int i = threadIdx.x; i < K; i += BT) hist[i] = 0;
    __syncthreads();
    ll base = (ll)blockIdx.x * CHUNKD;
    ll lim = base + CHUNKD;
    if (lim > RT) lim = RT;
    for (ll t = base + threadIdx.x; t < lim; t += BT) {
        int key = decode_key(t, uiR, u1s, u1d, u2s, u2d, i1s, i1d, i2s, i2d,
                             E2, EU1, EU2, EI1, EI2, N, U, I, M);
        atomicAdd(&hist[key >> BIN_SHIFT], 1);
    }
    __syncthreads();
    ll wb = (ll)blockIdx.x * K;
    for (int k = threadIdx.x; k < K; k += BT) {
        int h = hist[k];
        whist[wb + k] = h;
        if (h) atomicAdd(&btot[k * 32], h);
    }
}

// ---------------- bucket scan: totals -> bases, init cursors ----------------
__global__ __launch_bounds__(1024) void k_bscan(const int* __restrict__ btot,
                                                int* __restrict__ bbase,
                                                int* __restrict__ bcursor, const int K) {
    __shared__ int sh[1024];
    __shared__ int carry;
    int t = threadIdx.x;
    if (t == 0) carry = 0;
    __syncthreads();
    for (int base = 0; base < K; base += 1024) {
        int idx = base + t;
        int v = (idx < K) ? btot[idx * 32] : 0;
        sh[t] = v;
        __syncthreads();
        for (int off = 1; off < 1024; off <<= 1) {
            int x = (t >= off) ? sh[t - off] : 0;
            __syncthreads();
            sh[t] += x;
            __syncthreads();
        }
        if (idx < K) {
            int ex = carry + sh[t] - v;
            bbase[idx] = ex;
            bcursor[idx * 32] = ex;
        }
        __syncthreads();
        if (t == 0) carry += sh[1023];
        __syncthreads();
    }
}

// ---------------- pass A2: scatter (single decode pass) -------
__global__ __launch_bounds__(BT) void kA_scatter(
    const int* __restrict__ uiR, const int* __restrict__ uiC,
    const int* __restrict__ u1s, const int* __restrict__ u1d,
    const int* __restrict__ u2s, const int* __restrict__ u2d,
    const int* __restrict__ i1s, const int* __restrict__ i1d,
    const int* __restrict__ i2s, const int* __restrict__ i2d,
    const ll E2, const ll EU1, const ll EU2, const ll EI1, const ll EI2,
    const int N, const int U, const int I, const int M,
    const ll RT, const ll CHUNKD, const int K, int* __restrict__ bcursor,
    const int* __restrict__ whist,
    unsigned* __restrict__ binned) {
    __shared__ int lcur[KMAX];
    ll wb = (ll)blockIdx.x * K;
    for (int k = threadIdx.x; k < K; k += BT) {
        int h = whist[wb + k];
        lcur[k] = h ? atomicAdd(&bcursor[k * 32], h) : 0;
    }
    __syncthreads();
    ll base = (ll)blockIdx.x * CHUNKD;
    ll lim = base + CHUNKD;
    if (lim > RT) lim = RT;
    for (ll t = base + threadIdx.x; t < lim; t += BT) {
        int key, col;
        decode_rec(t, DECODE_ARGS, key, col);
        int pos = atomicAdd(&lcur[key >> BIN_SHIFT], 1);
        binned[pos] = ((unsigned)(key & 255) << 24) | (unsigned)col;
    }
}

// ---------------- pass B1: per-bucket LDS count -> counts array ----------
__global__ __launch_bounds__(256) void kB1_count(const unsigned* __restrict__ binned,
                                                 const int* __restrict__ bbase,
                                                 const int* __restrict__ btot,
                                                 int* __restrict__ counts, const int M2) {
    __shared__ int cnt[BIN_SIZE];
    int b = blockIdx.x;
    int lo = b << BIN_SHIFT;
    int hi = min(lo + BIN_SIZE, M2);
    for (int i = threadIdx.x; i < BIN_SIZE; i += 256) cnt[i] = 0;
    __syncthreads();
    int s = bbase[b], n = btot[b * 32];
    for (int j = s + threadIdx.x; j < s + n; j += 256) {
        atomicAdd(&cnt[binned[j] >> 24], 1);
    }
    __syncthreads();
    for (int i = threadIdx.x; i < hi - lo; i += 256) counts[lo + i] = cnt[i];
}

// ---------------- fused norms ----------------
__global__ void k_norm_all(const int* __restrict__ counts, float* __restrict__ nrm,
                           const int N, const int total) {
    int i = blockIdx.x * blockDim.x + threadIdx.x;
    if (i < total) {
        int c = counts[i];
        if (i < N) nrm[i] = (c > 0) ? (1.0f / sqrtf((float)c)) : 0.0f;
        else nrm[i] = 1.0f / sqrtf(fmaxf((float)c, 1.0f));
    }
}

// ---------------- hierarchical exclusive scan ----------
#define SCAN_T 256
#define SCAN_ELEMS 8
#define SCAN_CHUNK (SCAN_T * SCAN_ELEMS)   // 2048

__global__ __launch_bounds__(256) void k_scanA(const int* __restrict__ in, const int n,
                                               int* __restrict__ out, int* __restrict__ bsum) {
    __shared__ int sh[SCAN_T];
    int t = threadIdx.x;
    ll base = (ll)blockIdx.x * SCAN_CHUNK + (ll)t * SCAN_ELEMS;
    int v[SCAN_ELEMS];
    int tot = 0;
#pragma unroll
    for (int k = 0; k < SCAN_ELEMS; k++) {
        ll i = base + k;
        v[k] = (i < n) ? in[i] : 0;
        tot += v[k];
    }
    sh[t] = tot;
    __syncthreads();
    for (int off = 1; off < SCAN_T; off <<= 1) {
        int x = (t >= off) ? sh[t - off] : 0;
        __syncthreads();
        sh[t] += x;
        __syncthreads();
    }
    int run = sh[t] - tot;
#pragma unroll
    for (int k = 0; k < SCAN_ELEMS; k++) {
        ll i = base + k;
        if (i < n) out[i] = run;
        run += v[k];
    }
    if (t == SCAN_T - 1) bsum[blockIdx.x] = sh[SCAN_T - 1];
}

__global__ __launch_bounds__(256) void k_scanB(int* __restrict__ bsum, const int nb) {
    __shared__ int sh[256];
    int t = threadIdx.x;
    int running = 0;
    for (int base = 0; base < nb; base += 256) {
        int idx = base + t;
        int v = (idx < nb) ? bsum[idx] : 0;
        sh[t] = v;
        __syncthreads();
        for (int off = 1; off < 256; off <<= 1) {
            int x = (t >= off) ? sh[t - off] : 0;
            __syncthreads();
            sh[t] += x;
            __syncthreads();
        }
        if (idx < nb) bsum[idx] = running + sh[t] - v;
        int tot = sh[255];
        __syncthreads();
        running += tot;
    }
}

__global__ void k_scanC(int* __restrict__ S, const int n, const int* __restrict__ bsum, const int ET) {
    ll i = (ll)blockIdx.x * blockDim.x + threadIdx.x;
    if (i < n) S[i] += bsum[i / SCAN_CHUNK];
    if (i == 0) S[n] = ET;
}

// ---------------- pass B2: per-bucket CSR fill, LDS-staged ----------
__global__ __launch_bounds__(256) void kB2_fill(const unsigned* __restrict__ binned,
                                                const int* __restrict__ bbase,
                                                const int* __restrict__ btot,
                                                const int* __restrict__ S,
                                                const float* __restrict__ nrm,
                                                const int N, const int U, const int I,
                                                const int M,
                                                int2* __restrict__ ev_all) {
    __shared__ int scur[BIN_SIZE];
    __shared__ int2 buf[FILL_CAP];
    int b = blockIdx.x;
    int lo = b << BIN_SHIFT;
    int hi = min(lo + BIN_SIZE, M);
    int obase = S[lo];
    int nfill = S[hi] - obase;
    int s = bbase[b], n = btot[b * 32];
    const int segU = N + U, seg2U = N + 2 * U, segI = N + 2 * U + I;
    if (n <= FILL_CAP) {
        for (int i = threadIdx.x; i < hi - lo; i += 256) scur[i] = S[lo + i] - obase;
        __syncthreads();
        for (int j = s + threadIdx.x; j < s + n; j += 256) {
            unsigned rec = binned[j];
            int key = lo + (int)(rec >> 24);
            if (key < M) {
                int pos = atomicAdd(&scur[key - lo], 1);
                int col = (int)(rec & 0xFFFFFFu);
                int nidx;
                if (key < N)          nidx = col;                   // ui: dinv[col]
                else if (key < segU)  nidx = M + col;               // u1 src out-deg norm
                else if (key < seg2U) nidx = M + U + col;           // u2
                else if (key < segI)  nidx = M + 2 * U + col;       // i1
                else                  nidx = M + 2 * U + I + col;   // i2
                buf[pos] = make_int2(col * 64, __float_as_int(nrm[nidx]));
            }
        }
        __syncthreads();
        for (int i = threadIdx.x; i < nfill; i += 256)
            ev_all[obase + i] = buf[i];
    } else {
        // fallback: direct scatter (correct for any bucket size)
        for (int i = threadIdx.x; i < hi - lo; i += 256) scur[i] = S[lo + i];
        __syncthreads();
        for (int j = s + threadIdx.x; j < s + n; j += 256) {
            unsigned rec = binned[j];
            int key = lo + (int)(rec >> 24);
            if (key < M) {
                int pos = atomicAdd(&scur[key - lo], 1);
                int col = (int)(rec & 0xFFFFFFu);
                int nidx;
                if (key < N)          nidx = col;
                else if (key < segU)  nidx = M + col;
                else if (key < seg2U) nidx = M + U + col;
                else if (key < segI)  nidx = M + 2 * U + col;
                else                  nidx = M + 2 * U + I + col;
                ev_all[pos] = make_int2(col * 64, __float_as_int(nrm[nidx]));
            }
        }
    }
}

// ---------------- init features (bf16 storage) ----------------
__global__ void k_init(const void* __restrict__ uf, const void* __restrict__ itf,
                       ushort_t* __restrict__ ui, ushort_t* __restrict__ hu,
                       ushort_t* __restrict__ hi,
                       const ll nu64, const ll ntot64, const int* __restrict__ flag) {
    ll t = (ll)blockIdx.x * blockDim.x + threadIdx.x;
    int bf = *flag;
    if (t < nu64) {
        ushort_t v = bf ? ((const ushort_t*)uf)[t] : f2bf(((const float*)uf)[t]);
        ui[t] = v; hu[t] = v;
    } else if (t < ntot64) {
        ll j = t - nu64;
        ushort_t v = bf ? ((const ushort_t*)itf)[j] : f2bf(((const float*)itf)[j]);
        ui[t] = v; hi[j] = v;
    }
}

// ---------------- fused 5-segment gather SpMM, 8 lanes/row ----------------
// R10 (16 lanes/row, 4 chains/wave) cut gather 195->140us; still latency-
// leaning (HBM-path 2.2TB/s, VALU 39%). 8 lanes/row (bf16x8 = 16B per lane)
// puts 8 independent edge-chains in flight per wave; same lines, same bytes.
__global__ __launch_bounds__(256) void k_gather5(const int* __restrict__ S,
                                                 const int2* __restrict__ ev,
                                                 const float* __restrict__ nrm,
                                                 const ushort_t* __restrict__ xui,
                                                 const ushort_t* __restrict__ xu,
                                                 const ushort_t* __restrict__ xi,
                                                 ushort_t* __restrict__ out_ui,
                                                 ushort_t* __restrict__ o_zu1,
                                                 ushort_t* __restrict__ o_zu2,
                                                 ushort_t* __restrict__ o_zi1,
                                                 ushort_t* __restrict__ o_zi2,
                                                 const int N, const int U, const int I,
                                                 const int M) {
    ll gt = (ll)blockIdx.x * blockDim.x + threadIdx.x;
    int w = (int)(gt >> 3);             // 8 threads per row
    int l8 = threadIdx.x & 7;           // covers dims [l8*8, l8*8+8)
    if (w >= M) return;
    const ushort_t* x;
    ushort_t* out;
    int orow;
    if (w < N)                  { x = xui; out = out_ui; orow = w; }
    else if (w < N + U)         { x = xu;  out = o_zu1;  orow = w - N; }
    else if (w < N + 2 * U)     { x = xu;  out = o_zu2;  orow = w - N - U; }
    else if (w < N + 2 * U + I) { x = xi;  out = o_zi1;  orow = w - N - 2 * U; }
    else                        { x = xi;  out = o_zi2;  orow = w - N - 2 * U - I; }
    int s = S[w], e = S[w + 1];
    float a0 = 0.f, a1 = 0.f, a2 = 0.f, a3 = 0.f;
    float a4 = 0.f, a5 = 0.f, a6 = 0.f, a7 = 0.f;
    unsigned doff = (unsigned)(l8 * 8);
    for (int j = s; j < e; j += 4) {
#pragma unroll
        for (int k = 0; k < 4; k++) {
            int jj = j + k;
            bool live = jj < e;
            int2 pr = ev[live ? jj : s];
            float nn = live ? __int_as_float(pr.y) : 0.0f;
            unsigned off = (unsigned)pr.x + doff;
            bf16x8 xv = *(const bf16x8*)&x[off];     // 16B
            a0 += bf2f((ushort_t)xv[0]) * nn;
            a1 += bf2f((ushort_t)xv[1]) * nn;
            a2 += bf2f((ushort_t)xv[2]) * nn;
            a3 += bf2f((ushort_t)xv[3]) * nn;
            a4 += bf2f((ushort_t)xv[4]) * nn;
            a5 += bf2f((ushort_t)xv[5]) * nn;
            a6 += bf2f((ushort_t)xv[6]) * nn;
            a7 += bf2f((ushort_t)xv[7]) * nn;
        }
    }
    float rn = nrm[w];
    bf16x8 o;
    o[0] = (short)f2bf(a0 * rn); o[1] = (short)f2bf(a1 * rn);
    o[2] = (short)f2bf(a2 * rn); o[3] = (short)f2bf(a3 * rn);
    o[4] = (short)f2bf(a4 * rn); o[5] = (short)f2bf(a5 * rn);
    o[6] = (short)f2bf(a6 * rn); o[7] = (short)f2bf(a7 * rn);
    *(bf16x8*)&out[(ll)orow * 64 + doff] = o;
}

// ---------------- fast tanh ----------
__device__ __forceinline__ float fast_tanh(float x) {
    return 1.0f - 2.0f / (__expf(2.0f * x) + 1.0f);
}

// ---------------- MFMA semantic-attention scores, fused U+I halves --------
__global__ __launch_bounds__(256) void k_attn2(const ushort_t* __restrict__ zu1,
                                               const ushort_t* __restrict__ zu2,
                                               const ushort_t* __restrict__ Wbu,
                                               const float* __restrict__ b1u,
                                               const float* __restrict__ w2u,
                                               const int nU, float* __restrict__ wsU,
                                               const ushort_t* __restrict__ zi1,
                                               const ushort_t* __restrict__ zi2,
                                               const ushort_t* __restrict__ Wbi,
                                               const float* __restrict__ b1f_i,
                                               const float* __restrict__ w2f_i,
                                               const int nI, float* __restrict__ wsI,
                                               const int half) {
    __shared__ float red0[4], red1[4];
    bool isU = (int)blockIdx.x < half;
    const ushort_t* z1 = isU ? zu1 : zi1;
    const ushort_t* z2 = isU ? zu2 : zi2;
    const ushort_t* Wb = isU ? Wbu : Wbi;
    const float* b1f = isU ? b1u : b1f_i;
    const float* w2f = isU ? w2u : w2f_i;
    const int n = isU ? nU : nI;
    float* wsum = isU ? wsU : wsI;
    int blk = isU ? (int)blockIdx.x : (int)blockIdx.x - half;

    int tid = threadIdx.x;
    int lane = tid & 63;
    int wid = tid >> 6;
    int col = lane & 15;
    int quad = lane >> 4;

    bf16x8 wb[8][2];
#pragma unroll
    for (int ht = 0; ht < 8; ht++) {
        int h = ht * 16 + col;
#pragma unroll
        for (int ks = 0; ks < 2; ks++) {
            wb[ht][ks] = *(const bf16x8*)&Wb[h * 64 + ks * 32 + quad * 8];
        }
    }
    float b1v[8], w2v[8];
#pragma unroll
    for (int ht = 0; ht < 8; ht++) {
        b1v[ht] = b1f[ht * 16 + col];
        w2v[ht] = w2f[ht * 16 + col];
    }

    float w0 = 0.0f, w1 = 0.0f;
    int ntiles = (n + 15) >> 4;
    int gw = blk * 4 + wid;
    int nw = half * 4;
    const bf16x8 zero8 = {0, 0, 0, 0, 0, 0, 0, 0};

    for (int tile = gw; tile < ntiles; tile += nw) {
        int nodeA = tile * 16 + col;
        bool va = nodeA < n;
        bf16x8 a1[2], a2[2];
#pragma unroll
        for (int ks = 0; ks < 2; ks++) {
            const bf16x8* p1 = (const bf16x8*)&z1[(ll)nodeA * 64 + ks * 32 + quad * 8];
            const bf16x8* p2 = (const bf16x8*)&z2[(ll)nodeA * 64 + ks * 32 + quad * 8];
            a1[ks] = va ? p1[0] : zero8;
            a2[ks] = va ? p2[0] : zero8;
        }
#pragma unroll
        for (int ht = 0; ht < 8; ht++) {
            f32x4 c1 = {0.f, 0.f, 0.f, 0.f};
            f32x4 c2 = {0.f, 0.f, 0.f, 0.f};
            c1 = __builtin_amdgcn_mfma_f32_16x16x32_bf16(a1[0], wb[ht][0], c1, 0, 0, 0);
            c1 = __builtin_amdgcn_mfma_f32_16x16x32_bf16(a1[1], wb[ht][1], c1, 0, 0, 0);
            c2 = __builtin_amdgcn_mfma_f32_16x16x32_bf16(a2[0], wb[ht][0], c2, 0, 0, 0);
            c2 = __builtin_amdgcn_mfma_f32_16x16x32_bf16(a2[1], wb[ht][1], c2, 0, 0, 0);
#pragma unroll
            for (int r = 0; r < 4; r++) {
                int node_row = tile * 16 + quad * 4 + r;
                bool vr = node_row < n;
                float t1 = fast_tanh(c1[r] + b1v[ht]) * w2v[ht];
                float t2 = fast_tanh(c2[r] + b1v[ht]) * w2v[ht];
                w0 += vr ? t1 : 0.0f;
                w1 += vr ? t2 : 0.0f;
            }
        }
    }

    for (int off = 32; off > 0; off >>= 1) {
        w0 += __shfl_down(w0, off);
        w1 += __shfl_down(w1, off);
    }
    if (lane == 0) { red0[wid] = w0; red1[wid] = w1; }
    __syncthreads();
    if (tid == 0) {
        atomicAdd(&wsum[0], red0[0] + red0[1] + red0[2] + red0[3]);
        atomicAdd(&wsum[1], red1[0] + red1[1] + red1[2] + red1[3]);
    }
}

// ---------------- fused combine (U then I), inline beta softmax ----------
__global__ void k_combine2(const ushort_t* __restrict__ zu1, const ushort_t* __restrict__ zu2,
                           const float* __restrict__ wsU, const float inv_nU,
                           ushort_t* __restrict__ hu, const ll nu64,
                           const ushort_t* __restrict__ zi1, const ushort_t* __restrict__ zi2,
                           const float* __restrict__ wsI, const float inv_nI,
                           ushort_t* __restrict__ hi, const ll ntot64) {
    ll t = (ll)blockIdx.x * blockDim.x + threadIdx.x;
    if (t < nu64) {
        float m0 = wsU[0] * inv_nU, m1 = wsU[1] * inv_nU;
        float mx = fmaxf(m0, m1);
        float e0 = __expf(m0 - mx), e1 = __expf(m1 - mx);
        float inv_s = 1.0f / (e0 + e1);
        hu[t] = f2bf((e0 * bf2f(zu1[t]) + e1 * bf2f(zu2[t])) * inv_s);
    } else if (t < ntot64) {
        ll j = t - nu64;
        float m0 = wsI[0] * inv_nI, m1 = wsI[1] * inv_nI;
        float mx = fmaxf(m0, m1);
        float e0 = __expf(m0 - mx), e1 = __expf(m1 - mx);
        float inv_s = 1.0f / (e0 + e1);
        hi[j] = f2bf((e0 * bf2f(zi1[j]) + e1 * bf2f(zi2[j])) * inv_s);
    }
}

// ---------------- fused output gather ----------------
__device__ __forceinline__ void store_out(void* out, ll i, float v, int isbf16) {
    if (isbf16) ((ushort_t*)out)[i] = f2bf(v);
    else ((float*)out)[i] = v;
}

__global__ void k_out(const ushort_t* __restrict__ hu, const ushort_t* __restrict__ hi,
                      const ushort_t* __restrict__ ui, const int* __restrict__ user_idx,
                      const int* __restrict__ item_idx, const int* __restrict__ neg_idx,
                      void* __restrict__ out, const int B, const ll U,
                      const int* __restrict__ flag) {
    ll t = (ll)blockIdx.x * blockDim.x + threadIdx.x;
    int bf = *flag;
    int d = (int)(t & 63);
    ll b = t >> 6;
    if (b < B) {
        int u = user_idx[b];
        float v = 0.5f * bf2f(hu[(ll)u * 64 + d]) + 0.5f * bf2f(ui[(ll)u * 64 + d]);
        store_out(out, b * 64 + d, v, bf);
    } else if (b < 2 * (ll)B) {
        ll bb = b - B;
        int it = item_idx[bb];
        float v = 0.5f * bf2f(hi[(ll)it * 64 + d]) + 0.5f * bf2f(ui[(U + it) * 64 + d]);
        store_out(out, (ll)B * 64 + bb * 64 + d, v, bf);
    } else if (b < 3 * (ll)B) {
        ll bb = b - 2 * (ll)B;
        int it = item_idx[neg_idx[bb]];
        float v = 0.5f * bf2f(hi[(ll)it * 64 + d]) + 0.5f * bf2f(ui[(U + it) * 64 + d]);
        store_out(out, (ll)2 * B * 64 + bb * 64 + d, v, bf);
    }
}

extern "C" void kernel_launch(void* const* d_in, const int* in_sizes, int n_in,
                              void* d_out, int out_size, void* d_ws, size_t ws_size,
                              hipStream_t stream) {
    const int D = 64;
    const ll U = in_sizes[0] / D;
    const ll I = in_sizes[1] / D;
    const ll N = U + I;
    const ll E2  = in_sizes[8] / 2;
    const ll EU1 = in_sizes[9] / 2;
    const ll EU2 = in_sizes[10] / 2;
    const ll EI1 = in_sizes[11] / 2;
    const ll EI2 = in_sizes[12] / 2;
    const ll ET = E2 + EU1 + EU2 + EI1 + EI2;
    const ll RT = E2 + 2 * (EU1 + EU2 + EI1 + EI2);   // binning records
    const int B = in_sizes[13];
    const int M = (int)(N + 2 * U + 2 * I);           // CSR/in-deg index space
    const int M2 = (int)(N + 4 * U + 4 * I);          // + out-deg space
    const int K = (M2 + BIN_SIZE - 1) >> BIN_SHIFT;   // buckets
    const int KM = (M + BIN_SIZE - 1) >> BIN_SHIFT;   // buckets covering [0,M)
    if (K > KMAX) return;

    const void* user_feat = d_in[0];
    const void* item_feat = d_in[1];
    const int* uiR = (const int*)d_in[8];
    const int* uiC = uiR + E2;
    const int* u1s = (const int*)d_in[9];
    const int* u1d = u1s + EU1;
    const int* u2s = (const int*)d_in[10];
    const int* u2d = u2s + EU2;
    const int* i1s = (const int*)d_in[11];
    const int* i1d = i1s + EI1;
    const int* i2s = (const int*)d_in[12];
    const int* i2d = i2s + EI2;
    const int* user_idx = (const int*)d_in[13];
    const int* item_idx = (const int*)d_in[14];
    const int* neg_idx  = (const int*)d_in[15];

    const int T = 256;
    // ~252 WGs of 16 waves each; chunk rounded up to BT multiple.
    const ll CHUNKD = ((RT + 251) / 252 + (ll)BT - 1) / (ll)BT * (ll)BT;
    const int nWG_A = cdiv_ll(RT, CHUNKD);

    // ---------------- workspace layout ----------------
    ushort_t* q = (ushort_t*)d_ws;
    ushort_t* ui0 = q; q += N * 64;
    ushort_t* ui1 = q; q += N * 64;
    ushort_t* zi1 = q; q += I * 64;
    ushort_t* zi2 = q; q += I * 64;
    ushort_t* zu1 = q; q += U * 64;
    ushort_t* zu2 = q; q += U * 64;
    ushort_t* hu  = q; q += U * 64;
    ushort_t* hi  = q; q += I * 64;
    size_t feat_bytes = (size_t)(q - (ushort_t*)d_ws) * 2;
    if (feat_bytes < (size_t)RT * 4) return;   // binned overlay must fit (4B records)
    unsigned* binned = (unsigned*)d_ws;

    float* p = (float*)(((uintptr_t)q + 15) & ~(uintptr_t)15);
    float* nrm = p;  p += M2;
    ushort_t* Wbu = (ushort_t*)p; p += 64 * 128 / 2;
    ushort_t* Wbi = (ushort_t*)p; p += 64 * 128 / 2;
    float* wb1u = p; p += 128;
    float* ww2u = p; p += 128;
    float* wb1i = p; p += 128;
    float* ww2i = p; p += 128;
    float* scratch = p; p += 16;

    int* ip = (int*)p;
    int* btot = ip;    ip += KMAX * 32;
    int* bbase = ip;   ip += KMAX;
    int* bcursor = ip; ip += KMAX * 32;
    int* counts = ip;  ip += M2;
    int* S = ip;       ip += M + 1;
    ip = (int*)(((uintptr_t)ip + 7) & ~(uintptr_t)7);
    int2* ev_all = (int2*)ip; ip += 2 * ET;           // fused (col*64, norm) payload
    int* whist = ip;   ip += (size_t)nWG_A * K;       // per-WG bucket histograms
    int* bsum = ip;    ip += 256;
    int* flag = ip;    ip += 4;
    size_t needed = (size_t)((char*)ip - (char*)d_ws);
    if (ws_size < needed) return;

    // ---------------- dtype detection + weight conversion ----------------
    k_detect<<<1, 256, 0, stream>>>((const unsigned int*)user_feat, (ll)in_sizes[0] / 2, flag);
    k_cvt_weights<<<cdiv_ll(2 * (64 * 128 + 256), T), T, 0, stream>>>(
        d_in[2], d_in[3], d_in[4], d_in[5], d_in[6], d_in[7],
        Wbu, wb1u, ww2u, Wbi, wb1i, ww2i, flag);

    // ---------------- CSR build via 2-level binning ----------------
    hipMemsetAsync(btot, 0, (size_t)KMAX * 32 * sizeof(int), stream);
    hipMemsetAsync(scratch, 0, 16 * sizeof(float), stream);
    kA_hist<<<nWG_A, BT, 0, stream>>>(uiR, u1s, u1d, u2s, u2d, i1s, i1d, i2s, i2d,
                                      E2, EU1, EU2, EI1, EI2, (int)N, (int)U, (int)I, M,
                                      RT, CHUNKD, K, btot, whist);
    k_bscan<<<1, 1024, 0, stream>>>(btot, bbase, bcursor, K);
    kA_scatter<<<nWG_A, BT, 0, stream>>>(uiR, uiC, u1s, u1d, u2s, u2d, i1s, i1d, i2s, i2d,
                                         E2, EU1, EU2, EI1, EI2, (int)N, (int)U, (int)I, M,
                                         RT, CHUNKD, K, bcursor, whist, binned);
    kB1_count<<<K, T, 0, stream>>>(binned, bbase, btot, counts, M2);
    k_norm_all<<<cdiv_ll(M2, T), T, 0, stream>>>(counts, nrm, (int)N, M2);
    {
        int nb = (M + SCAN_CHUNK - 1) / SCAN_CHUNK;
        k_scanA<<<nb, SCAN_T, 0, stream>>>(counts, M, S, bsum);
        k_scanB<<<1, 256, 0, stream>>>(bsum, nb);
        k_scanC<<<cdiv_ll(M, T), T, 0, stream>>>(S, M, bsum, (int)ET);
    }
    kB2_fill<<<KM, T, 0, stream>>>(binned, bbase, btot, S, nrm,
                                   (int)N, (int)U, (int)I, M, ev_all);

    // ---------------- init features (after binned is consumed) ----------------
    k_init<<<cdiv_ll(N * 64, T), T, 0, stream>>>(user_feat, item_feat, ui0, hu, hi, U * 64, N * 64, flag);

    ushort_t* uiA = ui0;
    ushort_t* uiB = ui1;
    const int ATTN_HALF = 512;

    for (int layer = 0; layer < 2; layer++) {
        float* wsU = scratch + (layer ? 8 : 0);
        float* wsI = scratch + (layer ? 12 : 4);

        // ---- fused 5-way gather (ui, u1, u2, i1, i2), 8 lanes/row ----
        k_gather5<<<cdiv_ll((ll)M * 8, T), T, 0, stream>>>(
            S, ev_all, nrm, uiA, hu, hi,
            uiB, zu1, zu2, zi1, zi2,
            (int)N, (int)U, (int)I, M);
        { ushort_t* tmp = uiA; uiA = uiB; uiB = tmp; }

        // ---- fused attention scores (U half + I half) ----
        k_attn2<<<2 * ATTN_HALF, T, 0, stream>>>(
            zu1, zu2, Wbu, wb1u, ww2u, (int)U, wsU,
            zi1, zi2, Wbi, wb1i, ww2i, (int)I, wsI, ATTN_HALF);

        // ---- fused combine (hu + hi) ----
        k_combine2<<<cdiv_ll((U + I) * 64, T), T, 0, stream>>>(
            zu1, zu2, wsU, 1.0f / (float)U, hu, U * 64,
            zi1, zi2, wsI, 1.0f / (float)I, hi, (U + I) * 64);
    }

    // ---------------- final ----------------
    k_out<<<cdiv_ll((ll)3 * B * 64, T), T, 0, stream>>>(hu, hi, uiA, user_idx, item_idx, neg_idx,
                                                        d_out, B, U, flag);
}